// Round 10
// baseline (174.673 us; speedup 1.0000x reference)
//
#include <hip/hip_runtime.h>

// CrossAttentionModel on MI355X (gfx950) — round 10.
//
// Math (softmax row-constant invariance + sum(w)=1):
//   Mt[f][e] = sum_a Wk[f][a] Wq[e][a]   (split-bf16 3-pass, stored fp16)
//   wvec[f]  = Wk bq ; cvec[e] = bv Wo + bo
//   q'[i][f] = (sum_e x[i][e] Mt[f][e] + wvec[f]) * log2(e)   (fp16)
//   scores'  = q' y^T  (base-2 softmax; 32x32x16 fp16 MFMA)
//   out      = (softmax2(scores') y) (Wv Wo) + cvec
//
// R10 vs R9: flash7 = flash6 body in 256-thr/4-wave/128-q blocks, grid 512
// = 2 independent blocks/CU (phase-decorrelated barrier domains; the one
// untested variable after barriers/conflicts/P-roundtrip all proved null).
// Per-tile gll double-buffer, 64KB LDS/block. qprime6 adds B-frag register
// double-buffer to hide L2 latency (was 1-deep on 8 loads per k-step).

#define DEV static __device__ __forceinline__

typedef __attribute__((ext_vector_type(8))) short s8v;        // 8 bf16
typedef __attribute__((ext_vector_type(8))) _Float16 h8v;     // 8 fp16
typedef __attribute__((ext_vector_type(4))) float f4v;
typedef __attribute__((ext_vector_type(16))) float f16f;
typedef __attribute__((ext_vector_type(4))) float float4v;
typedef __attribute__((ext_vector_type(4))) unsigned int u32x4;
typedef unsigned short u16;
typedef unsigned int u32;

constexpr int BB = 16;
constexpr int LQ = 1024;
constexpr int LK = 2048;
constexpr int E = 512;
constexpr int F = 256;

DEV u16 f2bf(float x) {
    u32 u = __builtin_bit_cast(u32, x);
    u += 0x7fff + ((u >> 16) & 1);
    return (u16)(u >> 16);
}
DEV float bf2f(u16 h) { return __builtin_bit_cast(float, (u32)h << 16); }

DEV f4v MF(s8v a, s8v b, f4v c) {
    return __builtin_amdgcn_mfma_f32_16x16x32_bf16(a, b, c, 0, 0, 0);
}
DEV f4v MF16(h8v a, h8v b, f4v c) {
    return __builtin_amdgcn_mfma_f32_16x16x32_f16(a, b, c, 0, 0, 0);
}
DEV f16f MF32(h8v a, h8v b, f16f c) {
    return __builtin_amdgcn_mfma_f32_32x32x16_f16(a, b, c, 0, 0, 0);
}
DEV u32 pkh(float a, float b) {               // pack 2 f32 -> 2 f16 (RTZ)
    auto t = __builtin_amdgcn_cvt_pkrtz(a, b);
    return __builtin_bit_cast(u32, t);
}

// global -> LDS async copy, 16 bytes per lane.
DEV void gll16(const _Float16* g, _Float16* l) {
    __builtin_amdgcn_global_load_lds(
        (const __attribute__((address_space(1))) u32*)g,
        (__attribute__((address_space(3))) u32*)l, 16, 0, 0);
}

// ---------------------------------------------------------------------------
// prew: fused weight preprocessing + y fragment prep (unchanged).
__global__ __launch_bounds__(256) void prew(
    const float* __restrict__ y, _Float16* __restrict__ yA,
    _Float16* __restrict__ yB,
    const float* __restrict__ Wq, const float* __restrict__ bq,
    const float* __restrict__ Wk, const float* __restrict__ Wv,
    const float* __restrict__ bv, const float* __restrict__ Wo,
    const float* __restrict__ bo,
    u16* __restrict__ Mhb, u16* __restrict__ Ntb,
    float* __restrict__ wvec, float* __restrict__ cvec)
{
    __shared__ __align__(16) char smem[33536];
    const int tid = threadIdx.x;
    const int bi = blockIdx.x;

    if (bi < 1024) {
        float (*Y)[260] = (float(*)[260])smem;
        const int b = bi >> 6, t = bi & 63;
        const float* src = y + ((size_t)b * LK + t * 32) * F;
#pragma unroll
        for (int i = 0; i < 8; ++i) {
            int base = i * 1024 + tid * 4;
            int k = base >> 8, f = base & 255;
            *(float4v*)&Y[k][f] = *(const float4v*)(src + base);
        }
        __syncthreads();
        size_t tb = (size_t)(b * 64 + t) * 8192;
#pragma unroll
        for (int i = 0; i < 4; ++i) {
            int c = i * 256 + tid;
            int k = c & 31, hi = (c >> 5) & 1, fs = c >> 6;
            int f0 = fs * 16 + hi * 8;
            float4v v0 = *(const float4v*)&Y[k][f0];
            float4v v1 = *(const float4v*)&Y[k][f0 + 4];
            h8v v;
#pragma unroll
            for (int j = 0; j < 4; ++j) { v[j] = (_Float16)v0[j]; v[4 + j] = (_Float16)v1[j]; }
            *(h8v*)(yA + tb + (size_t)c * 8) = v;
        }
#pragma unroll
        for (int i = 0; i < 4; ++i) {
            int c = i * 256 + tid;
            int fl = c & 31, hi = (c >> 5) & 1, frag = c >> 6;
            int ft = frag >> 1, ks = frag & 1;
            int f = ft * 32 + fl, k0 = ks * 16 + hi * 8;
            h8v v;
#pragma unroll
            for (int j = 0; j < 8; ++j) v[j] = (_Float16)Y[k0 + j][f];
            *(h8v*)(yB + tb + (size_t)c * 8) = v;
        }
        return;
    }

    const int wb = bi - 1024;
    if (wb >= 64) {
        if (wb == 64) {
            const float* r = Wk + (size_t)tid * 512;
            float s = 0.f;
#pragma unroll 4
            for (int a = 0; a < 512; a += 4) {
                float4v v = *(const float4v*)(r + a);
                float4v bb = *(const float4v*)(bq + a);
                s += v[0] * bb[0] + v[1] * bb[1] + v[2] * bb[2] + v[3] * bb[3];
            }
            wvec[tid] = s;
        } else {
            int e = (wb - 65) * 256 + tid;
            float s = bo[e];
#pragma unroll 4
            for (int a = 0; a < 512; ++a) s += bv[a] * Wo[(size_t)a * 512 + e];
            cvec[e] = s;
        }
        return;
    }

    const bool ntm = wb >= 32;
    const int bj = ntm ? wb - 32 : wb;
    const int m0 = ntm ? (bj >> 2) * 64 : (bj >> 3) * 64;
    const int n0 = ntm ? (bj & 3) * 64 : (bj & 7) * 64;
    const float* Ag = ntm ? Wo : Wk;
    const float* Bg = ntm ? Wv : Wq;

    u16 (*Ash)[40] = (u16(*)[40])(smem);
    u16 (*Asl)[40] = (u16(*)[40])(smem + 5120);
    u16 (*Bsh)[40] = (u16(*)[40])(smem + 10240);
    u16 (*Bsl)[40] = (u16(*)[40])(smem + 15360);

    const int w = tid >> 6, lane = tid & 63;
    const int g = lane >> 4, qn = lane & 15;
    const int wr = w & 1, wc = w >> 1;

    f4v acc[2][2];
#pragma unroll
    for (int i = 0; i < 2; ++i)
#pragma unroll
        for (int j = 0; j < 2; ++j) acc[i][j] = (f4v){0.f, 0.f, 0.f, 0.f};

    for (int k0 = 0; k0 < 512; k0 += 32) {
        __syncthreads();
        if (!ntm) {
            int r = tid & 63, c = (tid >> 6) * 8;
            const float* s = Ag + (size_t)(m0 + r) * 512 + k0 + c;
            float4v v0 = *(const float4v*)s, v1 = *(const float4v*)(s + 4);
            short hh[8], ll[8];
#pragma unroll
            for (int i = 0; i < 8; ++i) {
                float x = (i < 4) ? v0[i] : v1[i - 4];
                u16 h = f2bf(x);
                hh[i] = (short)h;
                ll[i] = (short)f2bf(x - bf2f(h));
            }
            *(s8v*)&Ash[r][c] = (s8v){hh[0],hh[1],hh[2],hh[3],hh[4],hh[5],hh[6],hh[7]};
            *(s8v*)&Asl[r][c] = (s8v){ll[0],ll[1],ll[2],ll[3],ll[4],ll[5],ll[6],ll[7]};
        } else {
            int k = tid >> 3, mc = (tid & 7) * 8;
            const float* s = Ag + (size_t)(k0 + k) * 512 + m0 + mc;
            float4v v0 = *(const float4v*)s, v1 = *(const float4v*)(s + 4);
#pragma unroll
            for (int i = 0; i < 8; ++i) {
                float x = (i < 4) ? v0[i] : v1[i - 4];
                u16 h = f2bf(x);
                Ash[mc + i][k] = h;
                Asl[mc + i][k] = f2bf(x - bf2f(h));
            }
        }
        {
            int r = tid & 63, c = (tid >> 6) * 8;
            const float* s = Bg + (size_t)(n0 + r) * 512 + k0 + c;
            float4v v0 = *(const float4v*)s, v1 = *(const float4v*)(s + 4);
            short hh[8], ll[8];
#pragma unroll
            for (int i = 0; i < 8; ++i) {
                float x = (i < 4) ? v0[i] : v1[i - 4];
                u16 h = f2bf(x);
                hh[i] = (short)h;
                ll[i] = (short)f2bf(x - bf2f(h));
            }
            *(s8v*)&Bsh[r][c] = (s8v){hh[0],hh[1],hh[2],hh[3],hh[4],hh[5],hh[6],hh[7]};
            *(s8v*)&Bsl[r][c] = (s8v){ll[0],ll[1],ll[2],ll[3],ll[4],ll[5],ll[6],ll[7]};
        }
        __syncthreads();

        s8v ah[2], al[2], bh[2], bl[2];
#pragma unroll
        for (int mt = 0; mt < 2; ++mt) {
            ah[mt] = *(const s8v*)&Ash[wr * 32 + mt * 16 + qn][g * 8];
            al[mt] = *(const s8v*)&Asl[wr * 32 + mt * 16 + qn][g * 8];
        }
#pragma unroll
        for (int nt = 0; nt < 2; ++nt) {
            bh[nt] = *(const s8v*)&Bsh[wc * 32 + nt * 16 + qn][g * 8];
            bl[nt] = *(const s8v*)&Bsl[wc * 32 + nt * 16 + qn][g * 8];
        }
#pragma unroll
        for (int mt = 0; mt < 2; ++mt)
#pragma unroll
            for (int nt = 0; nt < 2; ++nt) {
                acc[mt][nt] = MF(ah[mt], bh[nt], acc[mt][nt]);
                acc[mt][nt] = MF(ah[mt], bl[nt], acc[mt][nt]);
                acc[mt][nt] = MF(al[mt], bh[nt], acc[mt][nt]);
            }
    }

#pragma unroll
    for (int mt = 0; mt < 2; ++mt)
#pragma unroll
        for (int nt = 0; nt < 2; ++nt)
#pragma unroll
            for (int r = 0; r < 4; ++r) {
                int gm = m0 + wr * 32 + mt * 16 + 4 * g + r;
                int gn = n0 + wc * 32 + nt * 16 + qn;
                float v = acc[mt][nt][r];
                if (!ntm) {
                    size_t off = (size_t)((gn >> 5) * 16 + (gm >> 4)) * 512 +
                                 (gm & 15) * 8 + ((gn >> 3) & 3) * 128 + (gn & 7);
                    Mhb[off] = __builtin_bit_cast(u16, (_Float16)v);
                } else {
                    size_t off = (size_t)((gn >> 5) * 32 + (gm >> 4)) * 512 +
                                 (gm & 15) * 8 + ((gn >> 3) & 3) * 128 + (gn & 7);
                    Ntb[off] = __builtin_bit_cast(u16, (_Float16)v);
                }
            }
}

// ---------------------------------------------------------------------------
// qprime6: q' = (x @ Mt + wvec) * log2e -> fp16. 64-row tiles, grid (256, 2).
// B-frag register double-buffer: prefetch k+1's 8 frags during k's MFMAs.
__global__ __launch_bounds__(256) void qprime6(
    const float* __restrict__ x, const u16* __restrict__ Mhb,
    const float* __restrict__ wv, _Float16* __restrict__ q16)
{
    __shared__ _Float16 Xs[2][64][40];
    const int tid = threadIdx.x, w = tid >> 6, lane = tid & 63;
    const int g = lane >> 4, qn = lane & 15;
    const int m0 = blockIdx.x * 64;
    const int nh = blockIdx.y * 8;
    const int srow = tid >> 2, scol = (tid & 3) * 8;
    const _Float16* Mh = (const _Float16*)Mhb;

    f4v acc[8];
#pragma unroll
    for (int n = 0; n < 8; ++n) acc[n] = (f4v){0.f, 0.f, 0.f, 0.f};

    float4v a0, a1;
    auto LDA = [&](int k0) {
        const float* s = x + (size_t)(m0 + srow) * 512 + k0 + scol;
        a0 = *(const float4v*)s;
        a1 = *(const float4v*)(s + 4);
    };
    auto STA = [&](int buf) {
        h8v v;
#pragma unroll
        for (int j = 0; j < 4; ++j) { v[j] = (_Float16)a0[j]; v[4 + j] = (_Float16)a1[j]; }
        *(h8v*)&Xs[buf][srow][scol] = v;
    };
    h8v b0[8], b1[8];
    auto LDB0 = [&](int t) {
        const int fb = t * 16 + nh;
#pragma unroll
        for (int nt = 0; nt < 8; ++nt)
            b0[nt] = *(const h8v*)(Mh + (size_t)(fb + nt) * 512 + lane * 8);
    };
    auto LDB1 = [&](int t) {
        const int fb = t * 16 + nh;
#pragma unroll
        for (int nt = 0; nt < 8; ++nt)
            b1[nt] = *(const h8v*)(Mh + (size_t)(fb + nt) * 512 + lane * 8);
    };

    LDA(0); STA(0); LDA(32); LDB0(0);
    __syncthreads();

#pragma unroll
    for (int t = 0; t < 16; ++t) {
        const int cur = t & 1;
        if (t < 15) { if (cur == 0) LDB1(t + 1); else LDB0(t + 1); }
        h8v af = *(const h8v*)&Xs[cur][w * 16 + qn][g * 8];
        if (cur == 0) {
#pragma unroll
            for (int nt = 0; nt < 8; ++nt) acc[nt] = MF16(af, b0[nt], acc[nt]);
        } else {
#pragma unroll
            for (int nt = 0; nt < 8; ++nt) acc[nt] = MF16(af, b1[nt], acc[nt]);
        }
        if (t < 15) {
            STA(cur ^ 1);
            if (t < 14) LDA((t + 2) * 32);
            __syncthreads();
        }
    }

#pragma unroll
    for (int nt = 0; nt < 8; ++nt) {
        int col = (nh + nt) * 16 + qn;
        float wvc = wv[col];
#pragma unroll
        for (int r = 0; r < 4; ++r) {
            int row = m0 + w * 16 + 4 * g + r;
            q16[(size_t)row * 256 + col] =
                (_Float16)((acc[nt][r] + wvc) * 1.44269504f);
        }
    }
}

// ---------------------------------------------------------------------------
// flash7: flash6 compute body; 256 thr = 4 waves x 32 q (128 q/block);
// grid 512 = 2 independent blocks/CU; per-32-key-tile gll double-buffer
// (64KB LDS); in-reg P; exp2 softmax; defer-max thr=11.54.
__global__ __launch_bounds__(256) void flash7(
    const _Float16* __restrict__ q16, const _Float16* __restrict__ yA,
    const _Float16* __restrict__ yB, _Float16* __restrict__ part,
    float* __restrict__ ml)
{
    __shared__ _Float16 Asb[2][8192];   // 32KB
    __shared__ _Float16 Bsb[2][8192];   // 32KB

    const int tid = threadIdx.x;
    const int lane = tid & 63;
    const int q32 = lane & 31;
    const int hi = lane >> 5;

    int id = blockIdx.x;
    int xcd = id & 7, slot = id >> 3;        // slot 0..63
    int grp = xcd + 8 * (slot >> 3);         // 0..63 = (b,z), pinned to xcd
    int qb = slot & 7;
    int b = grp >> 2, z = grp & 3;
    const int qw = qb * 128 + (tid >> 6) * 32;

    h8v qf[16];
    {
        const _Float16* qp = q16 + ((size_t)b * LQ + qw + q32) * 256 + hi * 8;
#pragma unroll
        for (int s = 0; s < 16; ++s) qf[s] = *(const h8v*)(qp + s * 16);
    }
    f16f ctx[8];
#pragma unroll
    for (int i = 0; i < 8; ++i) ctx[i] = (f16f){};
    float mrun = -3.0e38f, lrun = 0.f;

    const size_t tbe = (size_t)(b * 64 + z * 16) * 8192;

    auto STAGE = [&](int t, int buf) {
        const _Float16* ga = yA + tbe + (size_t)t * 8192;
        const _Float16* gb = yB + tbe + (size_t)t * 8192;
#pragma unroll
        for (int i = 0; i < 4; ++i) {
            gll16(ga + tid * 8 + i * 2048, &Asb[buf][tid * 8 + i * 2048]);
            gll16(gb + tid * 8 + i * 2048, &Bsb[buf][tid * 8 + i * 2048]);
        }
    };

    STAGE(0, 0);
    __syncthreads();

    int buf = 0;
    for (int t = 0; t < 16; ++t) {
        if (t < 15) STAGE(t + 1, buf ^ 1);
        const _Float16* Ap = &Asb[buf][0];
        const _Float16* Bp = &Bsb[buf][0];
        // ---- scores: two independent MFMA chains, merged once
        f16f Sa = (f16f){}, Sb = (f16f){};
#pragma unroll
        for (int fs = 0; fs < 16; fs += 2) {
            h8v a0 = *(const h8v*)(Ap + fs * 512 + lane * 8);
            h8v a1 = *(const h8v*)(Ap + (fs + 1) * 512 + lane * 8);
            Sa = MF32(a0, qf[fs], Sa);
            Sb = MF32(a1, qf[fs + 1], Sb);
        }
        f16f S = Sa + Sb;
        // ---- softmax stats (base-2), defer-max thr = 8*log2e
        float mt = fmaxf(S[0], S[1]);
#pragma unroll
        for (int r = 2; r < 16; ++r) mt = fmaxf(mt, S[r]);
        mt = fmaxf(mt, __shfl_xor(mt, 32));
        if (!__all(mt <= mrun + 11.5416f)) {
            float mnew = fmaxf(mrun, mt);
            float alpha = exp2f(mrun - mnew);
            lrun *= alpha;
#pragma unroll
            for (int r = 0; r < 16; ++r) {
                int qr = (r & 3) + 8 * (r >> 2) + 4 * hi;
                float ar = __shfl(alpha, qr);
#pragma unroll
                for (int ft = 0; ft < 8; ++ft) ctx[ft][r] *= ar;
            }
            mrun = mnew;
        }
        float p[16], ps = 0.f;
#pragma unroll
        for (int r = 0; r < 16; ++r) { p[r] = exp2f(S[r] - mrun); ps += p[r]; }
        ps += __shfl_xor(ps, 32);
        lrun += ps;
        // ---- P -> PV A-frags IN REGISTER
        {
            u32 X0 = pkh(p[0], p[1]),   X1 = pkh(p[2], p[3]);
            u32 Y0 = pkh(p[4], p[5]),   Y1 = pkh(p[6], p[7]);
            u32 Z0 = pkh(p[8], p[9]),   Z1 = pkh(p[10], p[11]);
            u32 W0 = pkh(p[12], p[13]), W1 = pkh(p[14], p[15]);
            u32 M0 = hi ? X0 : Y0, M1 = hi ? X1 : Y1;
            u32 N0 = hi ? Z0 : W0, N1 = hi ? Z1 : W1;
            u32 sM0 = __shfl_xor(M0, 32), sM1 = __shfl_xor(M1, 32);
            u32 sN0 = __shfl_xor(N0, 32), sN1 = __shfl_xor(N1, 32);
            u32x4 A0u = (u32x4){hi ? sM0 : X0, hi ? sM1 : X1,
                                hi ? Y0 : sM0, hi ? Y1 : sM1};
            u32x4 A1u = (u32x4){hi ? sN0 : Z0, hi ? sN1 : Z1,
                                hi ? W0 : sN0, hi ? W1 : sN1};
            h8v pa0 = __builtin_bit_cast(h8v, A0u);
            h8v pa1 = __builtin_bit_cast(h8v, A1u);
#pragma unroll
            for (int ft = 0; ft < 8; ++ft) {
                h8v bf = *(const h8v*)(Bp + (ft * 2 + 0) * 512 + lane * 8);
                ctx[ft] = MF32(pa0, bf, ctx[ft]);
            }
#pragma unroll
            for (int ft = 0; ft < 8; ++ft) {
                h8v bf = *(const h8v*)(Bp + (ft * 2 + 1) * 512 + lane * 8);
                ctx[ft] = MF32(pa1, bf, ctx[ft]);
            }
        }
        __syncthreads();
        buf ^= 1;
    }

    // ---- epilogue: normalized partials + (m, l)  (base-2 domain)
    float linv = 1.f / lrun;
    _Float16* pp = part + ((size_t)z * (BB * LQ) + (size_t)b * LQ + qw) * 256;
#pragma unroll
    for (int r = 0; r < 16; ++r) {
        int qr = (r & 3) + 8 * (r >> 2) + 4 * hi;
        float ir = __shfl(linv, qr);
#pragma unroll
        for (int ft = 0; ft < 8; ++ft)
            pp[(size_t)qr * 256 + ft * 32 + q32] = (_Float16)(ctx[ft][r] * ir);
    }
    if (hi == 0) {
        size_t mi = (size_t)z * (BB * LQ) + (size_t)b * LQ + qw + q32;
        ml[2 * mi + 0] = mrun;
        ml[2 * mi + 1] = lrun;
    }
}

// ---------------------------------------------------------------------------
// gemm2c: out = combine(part) @ Nt + cvec (base-2 combine). Unchanged.
__global__ __launch_bounds__(256) void gemm2c(
    const _Float16* __restrict__ part, const float* __restrict__ ml,
    const u16* __restrict__ Ntb, const float* __restrict__ cvec,
    float* __restrict__ out)
{
    __shared__ _Float16 Asb[64][40];
    __shared__ float scl[64][4];
    const int tid = threadIdx.x;
    const int w = tid >> 6, lane = tid & 63;
    const int g = lane >> 4, qn = lane & 15;
    const int wr = w >> 1, wc = w & 1;
    const int m0 = blockIdx.x * 64, e0 = blockIdx.y * 256;
    constexpr size_t PL = (size_t)BB * LQ * F;
    constexpr size_t PR = (size_t)BB * LQ;

    if (tid < 64) {
        size_t i = m0 + tid;
        float m0v = ml[2 * i], l0v = ml[2 * i + 1];
        float m1v = ml[2 * (PR + i)], l1v = ml[2 * (PR + i) + 1];
        float m2v = ml[2 * (2 * PR + i)], l2v = ml[2 * (2 * PR + i) + 1];
        float m3v = ml[2 * (3 * PR + i)], l3v = ml[2 * (3 * PR + i) + 1];
        float M = fmaxf(fmaxf(m0v, m1v), fmaxf(m2v, m3v));
        float e0v = exp2f(m0v - M), e1v = exp2f(m1v - M);
        float e2v = exp2f(m2v - M), e3v = exp2f(m3v - M);
        float inv = 1.f / (l0v * e0v + l1v * e1v + l2v * e2v + l3v * e3v);
        scl[tid][0] = l0v * e0v * inv;
        scl[tid][1] = l1v * e1v * inv;
        scl[tid][2] = l2v * e2v * inv;
        scl[tid][3] = l3v * e3v * inv;
    }

    f4v acc[2][8];
#pragma unroll
    for (int i = 0; i < 2; ++i)
#pragma unroll
        for (int j = 0; j < 8; ++j) acc[i][j] = (f4v){0.f, 0.f, 0.f, 0.f};

    for (int k0 = 0; k0 < F; k0 += 32) {
        __syncthreads();
        {
            int r = tid & 63, c = (tid >> 6) * 8;
            size_t base = (size_t)(m0 + r) * F + k0 + c;
            h8v p0 = *(const h8v*)(part + base);
            h8v p1 = *(const h8v*)(part + PL + base);
            h8v p2 = *(const h8v*)(part + 2 * PL + base);
            h8v p3 = *(const h8v*)(part + 3 * PL + base);
            float s0 = scl[r][0], s1 = scl[r][1], s2 = scl[r][2], s3 = scl[r][3];
#pragma unroll
            for (int i = 0; i < 8; ++i) {
                float v = (float)p0[i] * s0 + (float)p1[i] * s1 +
                          (float)p2[i] * s2 + (float)p3[i] * s3;
                Asb[r][c + i] = (_Float16)v;
            }
        }
        __syncthreads();

        h8v ah[2], bh[8];
#pragma unroll
        for (int mt = 0; mt < 2; ++mt)
            ah[mt] = *(const h8v*)&Asb[wr * 32 + mt * 16 + qn][g * 8];
        int eb = (e0 + wc * 128) >> 4;
#pragma unroll
        for (int nt = 0; nt < 8; ++nt)
            bh[nt] = *(const h8v*)((const _Float16*)Ntb +
                     (size_t)((k0 >> 5) * 32 + eb + nt) * 512 + lane * 8);
#pragma unroll
        for (int mt = 0; mt < 2; ++mt)
#pragma unroll
            for (int nt = 0; nt < 8; ++nt)
                acc[mt][nt] = MF16(ah[mt], bh[nt], acc[mt][nt]);
    }

#pragma unroll
    for (int mt = 0; mt < 2; ++mt)
#pragma unroll
        for (int nt = 0; nt < 8; ++nt)
#pragma unroll
            for (int r = 0; r < 4; ++r) {
                int gm = m0 + wr * 32 + mt * 16 + 4 * g + r;
                int gn = e0 + wc * 128 + nt * 16 + qn;
                out[(size_t)gm * E + gn] = acc[mt][nt][r] + cvec[gn];
            }
}

// ---------------------------------------------------------------------------
extern "C" void kernel_launch(void* const* d_in, const int* in_sizes, int n_in,
                              void* d_out, int out_size, void* d_ws, size_t ws_size,
                              hipStream_t stream)
{
    const float* x  = (const float*)d_in[0];   // [B,LQ,E]
    const float* y  = (const float*)d_in[1];   // [B,LK,F]
    const float* Wq = (const float*)d_in[2];
    const float* bq = (const float*)d_in[3];
    const float* Wk = (const float*)d_in[4];
    // d_in[5] = bk: per-row constant in scores -> softmax-invariant, unused.
    const float* Wv = (const float*)d_in[6];
    const float* bv = (const float*)d_in[7];
    const float* Wo = (const float*)d_in[8];
    const float* bo = (const float*)d_in[9];
    float* out = (float*)d_out;

    char* ws = (char*)d_ws;
    size_t off = 0;
    auto alloc = [&](size_t bytes) -> char* {
        char* p = ws + off;
        off = (off + bytes + 255) & ~(size_t)255;
        return p;
    };
    u16* Mhb  = (u16*)alloc(sizeof(u16) * F * E);
    float* wvec = (float*)alloc(sizeof(float) * F);
    float* cvec = (float*)alloc(sizeof(float) * E);
    u16* Ntb  = (u16*)alloc(sizeof(u16) * E * F);
    _Float16* q16 = (_Float16*)alloc(sizeof(u16) * (size_t)BB * LQ * F);
    _Float16* yA  = (_Float16*)alloc(sizeof(u16) * (size_t)BB * LK * F);
    _Float16* yB  = (_Float16*)alloc(sizeof(u16) * (size_t)BB * LK * F);
    _Float16* part = (_Float16*)alloc(sizeof(u16) * 4 * (size_t)BB * LQ * F);
    float* ml = (float*)alloc(sizeof(float) * 2 * 4 * (size_t)BB * LQ);
    (void)ws_size; (void)in_sizes; (void)n_in; (void)out_size;

    prew<<<dim3(1091), dim3(256), 0, stream>>>(
        y, yA, yB, Wq, bq, Wk, Wv, bv, Wo, bo, Mhb, Ntb, wvec, cvec);
    qprime6<<<dim3(BB * LQ / 64, 2), dim3(256), 0, stream>>>(x, Mhb, wvec, q16);
    flash7<<<dim3(512), dim3(256), 0, stream>>>(q16, yA, yB, part, ml);
    gemm2c<<<dim3(BB * LQ / 64, E / 256), dim3(256), 0, stream>>>(
        part, ml, Ntb, cvec, out);
}

// Round 11
// 135.685 us; speedup vs baseline: 1.2873x; 1.2873x over previous
//
#include <hip/hip_runtime.h>

// CrossAttentionModel on MI355X (gfx950) — round 11.
//
// Math (softmax row-constant invariance + sum(w)=1):
//   Mt[f][e] = sum_a Wk[f][a] Wq[e][a]   (split-bf16 3-pass, stored fp16)
//   wvec[f]  = Wk bq ; cvec[e] = bv Wo + bo
//   q'[i][f] = (sum_e x[i][e] Mt[f][e] + wvec[f]) * log2(e)   (fp16)
//   scores'  = q' y^T  (base-2 softmax; 32x32x16 fp16 MFMA)
//   out      = (softmax2(scores') y) (Wv Wo) + cvec
//
// R11: flash structure experiments concluded (5 variants, 57.5us plateau) —
// flash8 = R7's proven flash5 in exp2 domain. New focus: gemm2c2 reads the
// 33.5MB part buffer ONCE (was twice): 32-row x full-512-col blocks, grid
// 512 = 2 blocks/CU, combine in LDS shared across 4 wave col-blocks.

#define DEV static __device__ __forceinline__

typedef __attribute__((ext_vector_type(8))) short s8v;        // 8 bf16
typedef __attribute__((ext_vector_type(8))) _Float16 h8v;     // 8 fp16
typedef __attribute__((ext_vector_type(4))) _Float16 h4v;
typedef __attribute__((ext_vector_type(4))) float f4v;
typedef __attribute__((ext_vector_type(16))) float f16f;
typedef __attribute__((ext_vector_type(4))) float float4v;
typedef unsigned short u16;
typedef unsigned int u32;

constexpr int BB = 16;
constexpr int LQ = 1024;
constexpr int LK = 2048;
constexpr int E = 512;
constexpr int F = 256;

DEV u16 f2bf(float x) {
    u32 u = __builtin_bit_cast(u32, x);
    u += 0x7fff + ((u >> 16) & 1);
    return (u16)(u >> 16);
}
DEV float bf2f(u16 h) { return __builtin_bit_cast(float, (u32)h << 16); }

DEV f4v MF(s8v a, s8v b, f4v c) {
    return __builtin_amdgcn_mfma_f32_16x16x32_bf16(a, b, c, 0, 0, 0);
}
DEV f4v MF16(h8v a, h8v b, f4v c) {
    return __builtin_amdgcn_mfma_f32_16x16x32_f16(a, b, c, 0, 0, 0);
}
DEV f16f MF32(h8v a, h8v b, f16f c) {
    return __builtin_amdgcn_mfma_f32_32x32x16_f16(a, b, c, 0, 0, 0);
}

// global -> LDS async copy, 16 bytes per lane.
DEV void gll16(const _Float16* g, _Float16* l) {
    __builtin_amdgcn_global_load_lds(
        (const __attribute__((address_space(1))) u32*)g,
        (__attribute__((address_space(3))) u32*)l, 16, 0, 0);
}

// ---------------------------------------------------------------------------
// prew: fused weight preprocessing + y fragment prep (unchanged).
__global__ __launch_bounds__(256) void prew(
    const float* __restrict__ y, _Float16* __restrict__ yA,
    _Float16* __restrict__ yB,
    const float* __restrict__ Wq, const float* __restrict__ bq,
    const float* __restrict__ Wk, const float* __restrict__ Wv,
    const float* __restrict__ bv, const float* __restrict__ Wo,
    const float* __restrict__ bo,
    u16* __restrict__ Mhb, u16* __restrict__ Ntb,
    float* __restrict__ wvec, float* __restrict__ cvec)
{
    __shared__ __align__(16) char smem[33536];
    const int tid = threadIdx.x;
    const int bi = blockIdx.x;

    if (bi < 1024) {
        float (*Y)[260] = (float(*)[260])smem;
        const int b = bi >> 6, t = bi & 63;
        const float* src = y + ((size_t)b * LK + t * 32) * F;
#pragma unroll
        for (int i = 0; i < 8; ++i) {
            int base = i * 1024 + tid * 4;
            int k = base >> 8, f = base & 255;
            *(float4v*)&Y[k][f] = *(const float4v*)(src + base);
        }
        __syncthreads();
        size_t tb = (size_t)(b * 64 + t) * 8192;
#pragma unroll
        for (int i = 0; i < 4; ++i) {
            int c = i * 256 + tid;
            int k = c & 31, hi = (c >> 5) & 1, fs = c >> 6;
            int f0 = fs * 16 + hi * 8;
            float4v v0 = *(const float4v*)&Y[k][f0];
            float4v v1 = *(const float4v*)&Y[k][f0 + 4];
            h8v v;
#pragma unroll
            for (int j = 0; j < 4; ++j) { v[j] = (_Float16)v0[j]; v[4 + j] = (_Float16)v1[j]; }
            *(h8v*)(yA + tb + (size_t)c * 8) = v;
        }
#pragma unroll
        for (int i = 0; i < 4; ++i) {
            int c = i * 256 + tid;
            int fl = c & 31, hi = (c >> 5) & 1, frag = c >> 6;
            int ft = frag >> 1, ks = frag & 1;
            int f = ft * 32 + fl, k0 = ks * 16 + hi * 8;
            h8v v;
#pragma unroll
            for (int j = 0; j < 8; ++j) v[j] = (_Float16)Y[k0 + j][f];
            *(h8v*)(yB + tb + (size_t)c * 8) = v;
        }
        return;
    }

    const int wb = bi - 1024;
    if (wb >= 64) {
        if (wb == 64) {
            const float* r = Wk + (size_t)tid * 512;
            float s = 0.f;
#pragma unroll 4
            for (int a = 0; a < 512; a += 4) {
                float4v v = *(const float4v*)(r + a);
                float4v bb = *(const float4v*)(bq + a);
                s += v[0] * bb[0] + v[1] * bb[1] + v[2] * bb[2] + v[3] * bb[3];
            }
            wvec[tid] = s;
        } else {
            int e = (wb - 65) * 256 + tid;
            float s = bo[e];
#pragma unroll 4
            for (int a = 0; a < 512; ++a) s += bv[a] * Wo[(size_t)a * 512 + e];
            cvec[e] = s;
        }
        return;
    }

    const bool ntm = wb >= 32;
    const int bj = ntm ? wb - 32 : wb;
    const int m0 = ntm ? (bj >> 2) * 64 : (bj >> 3) * 64;
    const int n0 = ntm ? (bj & 3) * 64 : (bj & 7) * 64;
    const float* Ag = ntm ? Wo : Wk;
    const float* Bg = ntm ? Wv : Wq;

    u16 (*Ash)[40] = (u16(*)[40])(smem);
    u16 (*Asl)[40] = (u16(*)[40])(smem + 5120);
    u16 (*Bsh)[40] = (u16(*)[40])(smem + 10240);
    u16 (*Bsl)[40] = (u16(*)[40])(smem + 15360);

    const int w = tid >> 6, lane = tid & 63;
    const int g = lane >> 4, qn = lane & 15;
    const int wr = w & 1, wc = w >> 1;

    f4v acc[2][2];
#pragma unroll
    for (int i = 0; i < 2; ++i)
#pragma unroll
        for (int j = 0; j < 2; ++j) acc[i][j] = (f4v){0.f, 0.f, 0.f, 0.f};

    for (int k0 = 0; k0 < 512; k0 += 32) {
        __syncthreads();
        if (!ntm) {
            int r = tid & 63, c = (tid >> 6) * 8;
            const float* s = Ag + (size_t)(m0 + r) * 512 + k0 + c;
            float4v v0 = *(const float4v*)s, v1 = *(const float4v*)(s + 4);
            short hh[8], ll[8];
#pragma unroll
            for (int i = 0; i < 8; ++i) {
                float x = (i < 4) ? v0[i] : v1[i - 4];
                u16 h = f2bf(x);
                hh[i] = (short)h;
                ll[i] = (short)f2bf(x - bf2f(h));
            }
            *(s8v*)&Ash[r][c] = (s8v){hh[0],hh[1],hh[2],hh[3],hh[4],hh[5],hh[6],hh[7]};
            *(s8v*)&Asl[r][c] = (s8v){ll[0],ll[1],ll[2],ll[3],ll[4],ll[5],ll[6],ll[7]};
        } else {
            int k = tid >> 3, mc = (tid & 7) * 8;
            const float* s = Ag + (size_t)(k0 + k) * 512 + m0 + mc;
            float4v v0 = *(const float4v*)s, v1 = *(const float4v*)(s + 4);
#pragma unroll
            for (int i = 0; i < 8; ++i) {
                float x = (i < 4) ? v0[i] : v1[i - 4];
                u16 h = f2bf(x);
                Ash[mc + i][k] = h;
                Asl[mc + i][k] = f2bf(x - bf2f(h));
            }
        }
        {
            int r = tid & 63, c = (tid >> 6) * 8;
            const float* s = Bg + (size_t)(n0 + r) * 512 + k0 + c;
            float4v v0 = *(const float4v*)s, v1 = *(const float4v*)(s + 4);
            short hh[8], ll[8];
#pragma unroll
            for (int i = 0; i < 8; ++i) {
                float x = (i < 4) ? v0[i] : v1[i - 4];
                u16 h = f2bf(x);
                hh[i] = (short)h;
                ll[i] = (short)f2bf(x - bf2f(h));
            }
            *(s8v*)&Bsh[r][c] = (s8v){hh[0],hh[1],hh[2],hh[3],hh[4],hh[5],hh[6],hh[7]};
            *(s8v*)&Bsl[r][c] = (s8v){ll[0],ll[1],ll[2],ll[3],ll[4],ll[5],ll[6],ll[7]};
        }
        __syncthreads();

        s8v ah[2], al[2], bh[2], bl[2];
#pragma unroll
        for (int mt = 0; mt < 2; ++mt) {
            ah[mt] = *(const s8v*)&Ash[wr * 32 + mt * 16 + qn][g * 8];
            al[mt] = *(const s8v*)&Asl[wr * 32 + mt * 16 + qn][g * 8];
        }
#pragma unroll
        for (int nt = 0; nt < 2; ++nt) {
            bh[nt] = *(const s8v*)&Bsh[wc * 32 + nt * 16 + qn][g * 8];
            bl[nt] = *(const s8v*)&Bsl[wc * 32 + nt * 16 + qn][g * 8];
        }
#pragma unroll
        for (int mt = 0; mt < 2; ++mt)
#pragma unroll
            for (int nt = 0; nt < 2; ++nt) {
                acc[mt][nt] = MF(ah[mt], bh[nt], acc[mt][nt]);
                acc[mt][nt] = MF(ah[mt], bl[nt], acc[mt][nt]);
                acc[mt][nt] = MF(al[mt], bh[nt], acc[mt][nt]);
            }
    }

#pragma unroll
    for (int mt = 0; mt < 2; ++mt)
#pragma unroll
        for (int nt = 0; nt < 2; ++nt)
#pragma unroll
            for (int r = 0; r < 4; ++r) {
                int gm = m0 + wr * 32 + mt * 16 + 4 * g + r;
                int gn = n0 + wc * 32 + nt * 16 + qn;
                float v = acc[mt][nt][r];
                if (!ntm) {
                    size_t off = (size_t)((gn >> 5) * 16 + (gm >> 4)) * 512 +
                                 (gm & 15) * 8 + ((gn >> 3) & 3) * 128 + (gn & 7);
                    Mhb[off] = __builtin_bit_cast(u16, (_Float16)v);
                } else {
                    size_t off = (size_t)((gn >> 5) * 32 + (gm >> 4)) * 512 +
                                 (gm & 15) * 8 + ((gn >> 3) & 3) * 128 + (gn & 7);
                    Ntb[off] = __builtin_bit_cast(u16, (_Float16)v);
                }
            }
}

// ---------------------------------------------------------------------------
// qprime6: q' = (x @ Mt + wvec) * log2e -> fp16. 64-row tiles, grid (256, 2).
// B-frag register double-buffer (unchanged from R10).
__global__ __launch_bounds__(256) void qprime6(
    const float* __restrict__ x, const u16* __restrict__ Mhb,
    const float* __restrict__ wv, _Float16* __restrict__ q16)
{
    __shared__ _Float16 Xs[2][64][40];
    const int tid = threadIdx.x, w = tid >> 6, lane = tid & 63;
    const int g = lane >> 4, qn = lane & 15;
    const int m0 = blockIdx.x * 64;
    const int nh = blockIdx.y * 8;
    const int srow = tid >> 2, scol = (tid & 3) * 8;
    const _Float16* Mh = (const _Float16*)Mhb;

    f4v acc[8];
#pragma unroll
    for (int n = 0; n < 8; ++n) acc[n] = (f4v){0.f, 0.f, 0.f, 0.f};

    float4v a0, a1;
    auto LDA = [&](int k0) {
        const float* s = x + (size_t)(m0 + srow) * 512 + k0 + scol;
        a0 = *(const float4v*)s;
        a1 = *(const float4v*)(s + 4);
    };
    auto STA = [&](int buf) {
        h8v v;
#pragma unroll
        for (int j = 0; j < 4; ++j) { v[j] = (_Float16)a0[j]; v[4 + j] = (_Float16)a1[j]; }
        *(h8v*)&Xs[buf][srow][scol] = v;
    };
    h8v b0[8], b1[8];
    auto LDB0 = [&](int t) {
        const int fb = t * 16 + nh;
#pragma unroll
        for (int nt = 0; nt < 8; ++nt)
            b0[nt] = *(const h8v*)(Mh + (size_t)(fb + nt) * 512 + lane * 8);
    };
    auto LDB1 = [&](int t) {
        const int fb = t * 16 + nh;
#pragma unroll
        for (int nt = 0; nt < 8; ++nt)
            b1[nt] = *(const h8v*)(Mh + (size_t)(fb + nt) * 512 + lane * 8);
    };

    LDA(0); STA(0); LDA(32); LDB0(0);
    __syncthreads();

#pragma unroll
    for (int t = 0; t < 16; ++t) {
        const int cur = t & 1;
        if (t < 15) { if (cur == 0) LDB1(t + 1); else LDB0(t + 1); }
        h8v af = *(const h8v*)&Xs[cur][w * 16 + qn][g * 8];
        if (cur == 0) {
#pragma unroll
            for (int nt = 0; nt < 8; ++nt) acc[nt] = MF16(af, b0[nt], acc[nt]);
        } else {
#pragma unroll
            for (int nt = 0; nt < 8; ++nt) acc[nt] = MF16(af, b1[nt], acc[nt]);
        }
        if (t < 15) {
            STA(cur ^ 1);
            if (t < 14) LDA((t + 2) * 32);
            __syncthreads();
        }
    }

#pragma unroll
    for (int nt = 0; nt < 8; ++nt) {
        int col = (nh + nt) * 16 + qn;
        float wvc = wv[col];
#pragma unroll
        for (int r = 0; r < 4; ++r) {
            int row = m0 + w * 16 + 4 * g + r;
            q16[(size_t)row * 256 + col] =
                (_Float16)((acc[nt][r] + wvc) * 1.44269504f);
        }
    }
}

// ---------------------------------------------------------------------------
// flash8: R7's flash5 structure (proven 57.6us) in exp2 domain.
// grid 256 (qb, b, z) XCD-grouped; 512 thr = 8 waves x 32 q; gll dbuf
// 64-key supers; P via per-wave Pls; defer-max thr=11.54 (log2 units).
__global__ __launch_bounds__(512) void flash8(
    const _Float16* __restrict__ q16, const _Float16* __restrict__ yA,
    const _Float16* __restrict__ yB, _Float16* __restrict__ part,
    float* __restrict__ ml)
{
    __shared__ _Float16 Asb[2][2][8192];   // 64KB
    __shared__ _Float16 Bsb[2][2][8192];   // 64KB
    __shared__ _Float16 Pls[8][1024];      // 16KB

    const int tid = threadIdx.x;
    const int w = tid >> 6, lane = tid & 63;
    const int q32 = lane & 31, hi = lane >> 5;

    int id = blockIdx.x;
    int xcd = id & 7, slot = id >> 3;
    int grp = xcd + 8 * (slot >> 2);
    int qb = slot & 3;
    int b = grp >> 2, z = grp & 3;
    const int qw = qb * 256 + w * 32;

    h8v qf[16];
    {
        const _Float16* qp = q16 + ((size_t)b * LQ + qw + q32) * 256 + hi * 8;
#pragma unroll
        for (int s = 0; s < 16; ++s) qf[s] = *(const h8v*)(qp + s * 16);
    }
    f16f ctx[8];
#pragma unroll
    for (int i = 0; i < 8; ++i) ctx[i] = (f16f){};
    float mrun = -3.0e38f, lrun = 0.f;

    const size_t tbe = (size_t)(b * 64 + z * 16) * 8192;

    auto STAGE = [&](int sup, int buf) {
#pragma unroll
        for (int j = 0; j < 2; ++j) {
            const _Float16* ga = yA + tbe + (size_t)(sup * 2 + j) * 8192 + tid * 8;
            const _Float16* gb = yB + tbe + (size_t)(sup * 2 + j) * 8192 + tid * 8;
            gll16(ga,        &Asb[buf][j][tid * 8]);
            gll16(ga + 4096, &Asb[buf][j][tid * 8 + 4096]);
            gll16(gb,        &Bsb[buf][j][tid * 8]);
            gll16(gb + 4096, &Bsb[buf][j][tid * 8 + 4096]);
        }
    };

    STAGE(0, 0);
    __syncthreads();

    int buf = 0;
    for (int s = 0; s < 8; ++s) {
        if (s < 7) STAGE(s + 1, buf ^ 1);
#pragma unroll
        for (int j = 0; j < 2; ++j) {
            const _Float16* Ap = &Asb[buf][j][0];
            const _Float16* Bp = &Bsb[buf][j][0];
            // ---- scores: S^T[32k][32q], A = y frags (LDS), B = qf (regs)
            f16f S = (f16f){};
#pragma unroll
            for (int fs = 0; fs < 16; ++fs) {
                h8v a = *(const h8v*)(Ap + fs * 512 + lane * 8);
                S = MF32(a, qf[fs], S);
            }
            // ---- softmax (base-2, per-lane col q = q32), defer-max
            float mt = S[0];
#pragma unroll
            for (int r = 1; r < 16; ++r) mt = fmaxf(mt, S[r]);
            mt = fmaxf(mt, __shfl_xor(mt, 32));
            if (!__all(mt <= mrun + 11.5416f)) {
                float mnew = fmaxf(mrun, mt);
                float alpha = exp2f(mrun - mnew);
                lrun *= alpha;
#pragma unroll
                for (int r = 0; r < 16; ++r) {
                    int qr = (r & 3) + 8 * (r >> 2) + 4 * hi;
                    float ar = __shfl(alpha, qr);
#pragma unroll
                    for (int ft = 0; ft < 8; ++ft) ctx[ft][r] *= ar;
                }
                mrun = mnew;
            }
            float p[16], ps = 0.f;
#pragma unroll
            for (int r = 0; r < 16; ++r) { p[r] = exp2f(S[r] - mrun); ps += p[r]; }
            ps += __shfl_xor(ps, 32);
            lrun += ps;
            // ---- P -> per-wave LDS (PV A-frag layout)
            {
                _Float16* pw = &Pls[w][0];
#pragma unroll
                for (int r2 = 0; r2 < 4; ++r2) {
                    h4v pk = (h4v){(_Float16)p[4 * r2], (_Float16)p[4 * r2 + 1],
                                   (_Float16)p[4 * r2 + 2], (_Float16)p[4 * r2 + 3]};
                    *(h4v*)(pw + (r2 >> 1) * 512 + (r2 & 1) * 256 + q32 * 8 + hi * 4) = pk;
                }
            }
            // ---- PV: ctx += P[32q][32k] y[32k][32f]
#pragma unroll
            for (int ks = 0; ks < 2; ++ks) {
                h8v pa = *(const h8v*)(&Pls[w][ks * 512] + lane * 8);
#pragma unroll
                for (int ft = 0; ft < 8; ++ft) {
                    h8v bf = *(const h8v*)(Bp + (ft * 2 + ks) * 512 + lane * 8);
                    ctx[ft] = MF32(pa, bf, ctx[ft]);
                }
            }
        }
        __syncthreads();
        buf ^= 1;
    }

    // ---- epilogue: normalized partials + (m, l)  (base-2 domain)
    float linv = 1.f / lrun;
    _Float16* pp = part + ((size_t)z * (BB * LQ) + (size_t)b * LQ + qw) * 256;
#pragma unroll
    for (int r = 0; r < 16; ++r) {
        int qr = (r & 3) + 8 * (r >> 2) + 4 * hi;
        float ir = __shfl(linv, qr);
#pragma unroll
        for (int ft = 0; ft < 8; ++ft)
            pp[(size_t)qr * 256 + ft * 32 + q32] = (_Float16)(ctx[ft][r] * ir);
    }
    if (hi == 0) {
        size_t mi = (size_t)z * (BB * LQ) + (size_t)b * LQ + qw + q32;
        ml[2 * mi + 0] = mrun;
        ml[2 * mi + 1] = lrun;
    }
}

// ---------------------------------------------------------------------------
// gemm2c2: out[i][e] = sum_f combine(part)[i][f] Nt[e][f] + cvec[e].
// 32-row x FULL-512-col blocks, grid 512 = 2 blocks/CU. part read ONCE
// (was twice with e-split): combine per k-step into LDS, used by all 4
// wave col-blocks. Combine weights in base-2 domain.
__global__ __launch_bounds__(256) void gemm2c2(
    const _Float16* __restrict__ part, const float* __restrict__ ml,
    const u16* __restrict__ Ntb, const float* __restrict__ cvec,
    float* __restrict__ out)
{
    __shared__ _Float16 Asb[32][40];
    __shared__ float scl[32][4];
    const int tid = threadIdx.x;
    const int w = tid >> 6, lane = tid & 63;
    const int g = lane >> 4, qn = lane & 15;
    const int m0 = blockIdx.x * 32;
    constexpr size_t PL = (size_t)BB * LQ * F;
    constexpr size_t PR = (size_t)BB * LQ;

    if (tid < 32) {
        size_t i = m0 + tid;
        float m0v = ml[2 * i], l0v = ml[2 * i + 1];
        float m1v = ml[2 * (PR + i)], l1v = ml[2 * (PR + i) + 1];
        float m2v = ml[2 * (2 * PR + i)], l2v = ml[2 * (2 * PR + i) + 1];
        float m3v = ml[2 * (3 * PR + i)], l3v = ml[2 * (3 * PR + i) + 1];
        float M = fmaxf(fmaxf(m0v, m1v), fmaxf(m2v, m3v));
        float e0v = exp2f(m0v - M), e1v = exp2f(m1v - M);
        float e2v = exp2f(m2v - M), e3v = exp2f(m3v - M);
        float inv = 1.f / (l0v * e0v + l1v * e1v + l2v * e2v + l3v * e3v);
        scl[tid][0] = l0v * e0v * inv;
        scl[tid][1] = l1v * e1v * inv;
        scl[tid][2] = l2v * e2v * inv;
        scl[tid][3] = l3v * e3v * inv;
    }

    f4v acc[2][8];
#pragma unroll
    for (int i = 0; i < 2; ++i)
#pragma unroll
        for (int j = 0; j < 8; ++j) acc[i][j] = (f4v){0.f, 0.f, 0.f, 0.f};

    for (int k0 = 0; k0 < F; k0 += 32) {
        __syncthreads();
        {
            int r = tid >> 3, cc = (tid & 7) * 4;       // 32 rows x 8 col-chunks
            size_t base = (size_t)(m0 + r) * F + k0 + cc;
            h4v p0 = *(const h4v*)(part + base);
            h4v p1 = *(const h4v*)(part + PL + base);
            h4v p2 = *(const h4v*)(part + 2 * PL + base);
            h4v p3 = *(const h4v*)(part + 3 * PL + base);
            float s0 = scl[r][0], s1 = scl[r][1], s2 = scl[r][2], s3 = scl[r][3];
#pragma unroll
            for (int i = 0; i < 4; ++i) {
                float v = (float)p0[i] * s0 + (float)p1[i] * s1 +
                          (float)p2[i] * s2 + (float)p3[i] * s3;
                Asb[r][cc + i] = (_Float16)v;
            }
        }
        __syncthreads();

        h8v ah[2];
#pragma unroll
        for (int mt = 0; mt < 2; ++mt)
            ah[mt] = *(const h8v*)&Asb[mt * 16 + qn][g * 8];
        // wave w owns e-cols [w*128, w*128+128): frag idx = (k0>>5)*32 + w*8 + nt
#pragma unroll
        for (int nt = 0; nt < 8; ++nt) {
            h8v bh = *(const h8v*)((const _Float16*)Ntb +
                     (size_t)((k0 >> 5) * 32 + w * 8 + nt) * 512 + lane * 8);
            acc[0][nt] = MF16(ah[0], bh, acc[0][nt]);
            acc[1][nt] = MF16(ah[1], bh, acc[1][nt]);
        }
    }

#pragma unroll
    for (int mt = 0; mt < 2; ++mt)
#pragma unroll
        for (int nt = 0; nt < 8; ++nt)
#pragma unroll
            for (int r = 0; r < 4; ++r) {
                int gm = m0 + mt * 16 + 4 * g + r;
                int gn = w * 128 + nt * 16 + qn;
                out[(size_t)gm * E + gn] = acc[mt][nt][r] + cvec[gn];
            }
}

// ---------------------------------------------------------------------------
extern "C" void kernel_launch(void* const* d_in, const int* in_sizes, int n_in,
                              void* d_out, int out_size, void* d_ws, size_t ws_size,
                              hipStream_t stream)
{
    const float* x  = (const float*)d_in[0];   // [B,LQ,E]
    const float* y  = (const float*)d_in[1];   // [B,LK,F]
    const float* Wq = (const float*)d_in[2];
    const float* bq = (const float*)d_in[3];
    const float* Wk = (const float*)d_in[4];
    // d_in[5] = bk: per-row constant in scores -> softmax-invariant, unused.
    const float* Wv = (const float*)d_in[6];
    const float* bv = (const float*)d_in[7];
    const float* Wo = (const float*)d_in[8];
    const float* bo = (const float*)d_in[9];
    float* out = (float*)d_out;

    char* ws = (char*)d_ws;
    size_t off = 0;
    auto alloc = [&](size_t bytes) -> char* {
        char* p = ws + off;
        off = (off + bytes + 255) & ~(size_t)255;
        return p;
    };
    u16* Mhb  = (u16*)alloc(sizeof(u16) * F * E);
    float* wvec = (float*)alloc(sizeof(float) * F);
    float* cvec = (float*)alloc(sizeof(float) * E);
    u16* Ntb  = (u16*)alloc(sizeof(u16) * E * F);
    _Float16* q16 = (_Float16*)alloc(sizeof(u16) * (size_t)BB * LQ * F);
    _Float16* yA  = (_Float16*)alloc(sizeof(u16) * (size_t)BB * LK * F);
    _Float16* yB  = (_Float16*)alloc(sizeof(u16) * (size_t)BB * LK * F);
    _Float16* part = (_Float16*)alloc(sizeof(u16) * 4 * (size_t)BB * LQ * F);
    float* ml = (float*)alloc(sizeof(float) * 2 * 4 * (size_t)BB * LQ);
    (void)ws_size; (void)in_sizes; (void)n_in; (void)out_size;

    prew<<<dim3(1091), dim3(256), 0, stream>>>(
        y, yA, yB, Wq, bq, Wk, Wv, bv, Wo, bo, Mhb, Ntb, wvec, cvec);
    qprime6<<<dim3(BB * LQ / 64, 2), dim3(256), 0, stream>>>(x, Mhb, wvec, q16);
    flash8<<<dim3(256), dim3(512), 0, stream>>>(q16, yA, yB, part, ml);
    gemm2c2<<<dim3(BB * LQ / 32), dim3(256), 0, stream>>>(
        part, ml, Ntb, cvec, out);
}

// Round 12
// 134.372 us; speedup vs baseline: 1.2999x; 1.0098x over previous
//
#include <hip/hip_runtime.h>

// CrossAttentionModel on MI355X (gfx950) — round 12.
//
// Math (softmax row-constant invariance + sum(w)=1):
//   Mt[f][e] = sum_a Wk[f][a] Wq[e][a]   (split-bf16 3-pass, stored fp16)
//   wvec[f]  = Wk bq ; cvec[e] = bv Wo + bo
//   q'[i][f] = sum_e x[i][e] Mt[f][e] + wvec[f]   (fp16)
//   scores   = q' y^T  (32x32x16 fp16 MFMA)
//   out      = (softmax(scores) y) (Wv Wo) + cvec
//
// R12: consolidation. flash9 = R7's proven flash5 verbatim (57.6us, __expf,
// thr 8) — R11's exp2f (libm, not v_exp) cost 4us, reverted. Launches:
// wgemm(67) -> prepq(1536: qprime blocks FIRST + y-prep blocks; latency-
// bound and memory-bound populations co-schedule) -> flash9 -> gemm2c2.

#define DEV static __device__ __forceinline__

typedef __attribute__((ext_vector_type(8))) short s8v;        // 8 bf16
typedef __attribute__((ext_vector_type(8))) _Float16 h8v;     // 8 fp16
typedef __attribute__((ext_vector_type(4))) _Float16 h4v;
typedef __attribute__((ext_vector_type(4))) float f4v;
typedef __attribute__((ext_vector_type(16))) float f16f;
typedef __attribute__((ext_vector_type(4))) float float4v;
typedef unsigned short u16;
typedef unsigned int u32;

constexpr int BB = 16;
constexpr int LQ = 1024;
constexpr int LK = 2048;
constexpr int E = 512;
constexpr int F = 256;

DEV u16 f2bf(float x) {
    u32 u = __builtin_bit_cast(u32, x);
    u += 0x7fff + ((u >> 16) & 1);
    return (u16)(u >> 16);
}
DEV float bf2f(u16 h) { return __builtin_bit_cast(float, (u32)h << 16); }

DEV f4v MF(s8v a, s8v b, f4v c) {
    return __builtin_amdgcn_mfma_f32_16x16x32_bf16(a, b, c, 0, 0, 0);
}
DEV f4v MF16(h8v a, h8v b, f4v c) {
    return __builtin_amdgcn_mfma_f32_16x16x32_f16(a, b, c, 0, 0, 0);
}
DEV f16f MF32(h8v a, h8v b, f16f c) {
    return __builtin_amdgcn_mfma_f32_32x32x16_f16(a, b, c, 0, 0, 0);
}

// global -> LDS async copy, 16 bytes per lane.
DEV void gll16(const _Float16* g, _Float16* l) {
    __builtin_amdgcn_global_load_lds(
        (const __attribute__((address_space(1))) u32*)g,
        (__attribute__((address_space(3))) u32*)l, 16, 0, 0);
}

// ---------------------------------------------------------------------------
// wgemm: weight preprocessing only (67 blocks).
//   bi 0..31 : Mt 64x64 tiles (split-bf16 3-pass) -> fp16 frag-blocked Mhb
//   bi 32..63: Nt 64x64 tiles -> fp16 frag-blocked Ntb
//   bi 64    : wvec ; bi 65,66: cvec
__global__ __launch_bounds__(256) void wgemm(
    const float* __restrict__ Wq, const float* __restrict__ bq,
    const float* __restrict__ Wk, const float* __restrict__ Wv,
    const float* __restrict__ bv, const float* __restrict__ Wo,
    const float* __restrict__ bo,
    u16* __restrict__ Mhb, u16* __restrict__ Ntb,
    float* __restrict__ wvec, float* __restrict__ cvec)
{
    const int bi = blockIdx.x;
    const int tid = threadIdx.x;
    if (bi >= 64) {
        if (bi == 64) {
            const float* r = Wk + (size_t)tid * 512;
            float s = 0.f;
#pragma unroll 4
            for (int a = 0; a < 512; a += 4) {
                float4v v = *(const float4v*)(r + a);
                float4v bb = *(const float4v*)(bq + a);
                s += v[0] * bb[0] + v[1] * bb[1] + v[2] * bb[2] + v[3] * bb[3];
            }
            wvec[tid] = s;
        } else {
            int e = (bi - 65) * 256 + tid;
            float s = bo[e];
#pragma unroll 4
            for (int a = 0; a < 512; ++a) s += bv[a] * Wo[(size_t)a * 512 + e];
            cvec[e] = s;
        }
        return;
    }

    __shared__ u16 Ash[64][40], Asl[64][40];
    __shared__ u16 Bsh[64][40], Bsl[64][40];

    const bool ntm = bi >= 32;
    const int bj = ntm ? bi - 32 : bi;
    const int m0 = ntm ? (bj >> 2) * 64 : (bj >> 3) * 64;
    const int n0 = ntm ? (bj & 3) * 64 : (bj & 7) * 64;
    const float* Ag = ntm ? Wo : Wk;
    const float* Bg = ntm ? Wv : Wq;

    const int w = tid >> 6, lane = tid & 63;
    const int g = lane >> 4, qn = lane & 15;
    const int wr = w & 1, wc = w >> 1;

    f4v acc[2][2];
#pragma unroll
    for (int i = 0; i < 2; ++i)
#pragma unroll
        for (int j = 0; j < 2; ++j) acc[i][j] = (f4v){0.f, 0.f, 0.f, 0.f};

    for (int k0 = 0; k0 < 512; k0 += 32) {
        __syncthreads();
        if (!ntm) {
            int r = tid & 63, c = (tid >> 6) * 8;
            const float* s = Ag + (size_t)(m0 + r) * 512 + k0 + c;
            float4v v0 = *(const float4v*)s, v1 = *(const float4v*)(s + 4);
            short hh[8], ll[8];
#pragma unroll
            for (int i = 0; i < 8; ++i) {
                float x = (i < 4) ? v0[i] : v1[i - 4];
                u16 h = f2bf(x);
                hh[i] = (short)h;
                ll[i] = (short)f2bf(x - bf2f(h));
            }
            *(s8v*)&Ash[r][c] = (s8v){hh[0],hh[1],hh[2],hh[3],hh[4],hh[5],hh[6],hh[7]};
            *(s8v*)&Asl[r][c] = (s8v){ll[0],ll[1],ll[2],ll[3],ll[4],ll[5],ll[6],ll[7]};
        } else {
            int k = tid >> 3, mc = (tid & 7) * 8;
            const float* s = Ag + (size_t)(k0 + k) * 512 + m0 + mc;
            float4v v0 = *(const float4v*)s, v1 = *(const float4v*)(s + 4);
#pragma unroll
            for (int i = 0; i < 8; ++i) {
                float x = (i < 4) ? v0[i] : v1[i - 4];
                u16 h = f2bf(x);
                Ash[mc + i][k] = h;
                Asl[mc + i][k] = f2bf(x - bf2f(h));
            }
        }
        {
            int r = tid & 63, c = (tid >> 6) * 8;
            const float* s = Bg + (size_t)(n0 + r) * 512 + k0 + c;
            float4v v0 = *(const float4v*)s, v1 = *(const float4v*)(s + 4);
            short hh[8], ll[8];
#pragma unroll
            for (int i = 0; i < 8; ++i) {
                float x = (i < 4) ? v0[i] : v1[i - 4];
                u16 h = f2bf(x);
                hh[i] = (short)h;
                ll[i] = (short)f2bf(x - bf2f(h));
            }
            *(s8v*)&Bsh[r][c] = (s8v){hh[0],hh[1],hh[2],hh[3],hh[4],hh[5],hh[6],hh[7]};
            *(s8v*)&Bsl[r][c] = (s8v){ll[0],ll[1],ll[2],ll[3],ll[4],ll[5],ll[6],ll[7]};
        }
        __syncthreads();

        s8v ah[2], al[2], bh[2], bl[2];
#pragma unroll
        for (int mt = 0; mt < 2; ++mt) {
            ah[mt] = *(const s8v*)&Ash[wr * 32 + mt * 16 + qn][g * 8];
            al[mt] = *(const s8v*)&Asl[wr * 32 + mt * 16 + qn][g * 8];
        }
#pragma unroll
        for (int nt = 0; nt < 2; ++nt) {
            bh[nt] = *(const s8v*)&Bsh[wc * 32 + nt * 16 + qn][g * 8];
            bl[nt] = *(const s8v*)&Bsl[wc * 32 + nt * 16 + qn][g * 8];
        }
#pragma unroll
        for (int mt = 0; mt < 2; ++mt)
#pragma unroll
            for (int nt = 0; nt < 2; ++nt) {
                acc[mt][nt] = MF(ah[mt], bh[nt], acc[mt][nt]);
                acc[mt][nt] = MF(ah[mt], bl[nt], acc[mt][nt]);
                acc[mt][nt] = MF(al[mt], bh[nt], acc[mt][nt]);
            }
    }

#pragma unroll
    for (int mt = 0; mt < 2; ++mt)
#pragma unroll
        for (int nt = 0; nt < 2; ++nt)
#pragma unroll
            for (int r = 0; r < 4; ++r) {
                int gm = m0 + wr * 32 + mt * 16 + 4 * g + r;
                int gn = n0 + wc * 32 + nt * 16 + qn;
                float v = acc[mt][nt][r];
                if (!ntm) {
                    size_t off = (size_t)((gn >> 5) * 16 + (gm >> 4)) * 512 +
                                 (gm & 15) * 8 + ((gn >> 3) & 3) * 128 + (gn & 7);
                    Mhb[off] = __builtin_bit_cast(u16, (_Float16)v);
                } else {
                    size_t off = (size_t)((gn >> 5) * 32 + (gm >> 4)) * 512 +
                                 (gm & 15) * 8 + ((gn >> 3) & 3) * 128 + (gn & 7);
                    Ntb[off] = __builtin_bit_cast(u16, (_Float16)v);
                }
            }
}

// ---------------------------------------------------------------------------
// prepq: fused qprime (bi 0..511, latency-bound, dispatched first) +
// y-frag-prep (bi 512..1535, memory-bound). Populations co-schedule.
__global__ __launch_bounds__(256) void prepq(
    const float* __restrict__ y, _Float16* __restrict__ yA,
    _Float16* __restrict__ yB,
    const float* __restrict__ x, const u16* __restrict__ Mhb,
    const float* __restrict__ wv, _Float16* __restrict__ q16)
{
    __shared__ __align__(16) char smem[33280];
    const int tid = threadIdx.x;
    const int bi = blockIdx.x;

    if (bi < 512) {
        // -------- qprime: q' = x @ Mt + wvec -> fp16 (B-frag reg dbuf) -----
        _Float16 (*Xs)[64][40] = (_Float16(*)[64][40])smem;
        const int w = tid >> 6, lane = tid & 63;
        const int g = lane >> 4, qn = lane & 15;
        const int m0 = (bi >> 1) * 64;
        const int nh = (bi & 1) * 8;
        const int srow = tid >> 2, scol = (tid & 3) * 8;
        const _Float16* Mh = (const _Float16*)Mhb;

        f4v acc[8];
#pragma unroll
        for (int n = 0; n < 8; ++n) acc[n] = (f4v){0.f, 0.f, 0.f, 0.f};

        float4v a0, a1;
        auto LDA = [&](int k0) {
            const float* s = x + (size_t)(m0 + srow) * 512 + k0 + scol;
            a0 = *(const float4v*)s;
            a1 = *(const float4v*)(s + 4);
        };
        auto STA = [&](int buf) {
            h8v v;
#pragma unroll
            for (int j = 0; j < 4; ++j) { v[j] = (_Float16)a0[j]; v[4 + j] = (_Float16)a1[j]; }
            *(h8v*)&Xs[buf][srow][scol] = v;
        };
        h8v b0[8], b1[8];
        auto LDB0 = [&](int t) {
            const int fb = t * 16 + nh;
#pragma unroll
            for (int nt = 0; nt < 8; ++nt)
                b0[nt] = *(const h8v*)(Mh + (size_t)(fb + nt) * 512 + lane * 8);
        };
        auto LDB1 = [&](int t) {
            const int fb = t * 16 + nh;
#pragma unroll
            for (int nt = 0; nt < 8; ++nt)
                b1[nt] = *(const h8v*)(Mh + (size_t)(fb + nt) * 512 + lane * 8);
        };

        LDA(0); STA(0); LDA(32); LDB0(0);
        __syncthreads();

#pragma unroll
        for (int t = 0; t < 16; ++t) {
            const int cur = t & 1;
            if (t < 15) { if (cur == 0) LDB1(t + 1); else LDB0(t + 1); }
            h8v af = *(const h8v*)&Xs[cur][w * 16 + qn][g * 8];
            if (cur == 0) {
#pragma unroll
                for (int nt = 0; nt < 8; ++nt) acc[nt] = MF16(af, b0[nt], acc[nt]);
            } else {
#pragma unroll
                for (int nt = 0; nt < 8; ++nt) acc[nt] = MF16(af, b1[nt], acc[nt]);
            }
            if (t < 15) {
                STA(cur ^ 1);
                if (t < 14) LDA((t + 2) * 32);
                __syncthreads();
            }
        }

#pragma unroll
        for (int nt = 0; nt < 8; ++nt) {
            int col = (nh + nt) * 16 + qn;
            float wvc = wv[col];
#pragma unroll
            for (int r = 0; r < 4; ++r) {
                int row = m0 + w * 16 + 4 * g + r;
                q16[(size_t)row * 256 + col] = (_Float16)(acc[nt][r] + wvc);
            }
        }
        return;
    }

    // -------- y-prep: y f32 -> fragment-blocked fp16 yA / yB --------------
    {
        const int pb = bi - 512;
        float (*Y)[260] = (float(*)[260])smem;
        const int b = pb >> 6, t = pb & 63;
        const float* src = y + ((size_t)b * LK + t * 32) * F;
#pragma unroll
        for (int i = 0; i < 8; ++i) {
            int base = i * 1024 + tid * 4;
            int k = base >> 8, f = base & 255;
            *(float4v*)&Y[k][f] = *(const float4v*)(src + base);
        }
        __syncthreads();
        size_t tb = (size_t)(b * 64 + t) * 8192;
#pragma unroll
        for (int i = 0; i < 4; ++i) {
            int c = i * 256 + tid;
            int k = c & 31, hi = (c >> 5) & 1, fs = c >> 6;
            int f0 = fs * 16 + hi * 8;
            float4v v0 = *(const float4v*)&Y[k][f0];
            float4v v1 = *(const float4v*)&Y[k][f0 + 4];
            h8v v;
#pragma unroll
            for (int j = 0; j < 4; ++j) { v[j] = (_Float16)v0[j]; v[4 + j] = (_Float16)v1[j]; }
            *(h8v*)(yA + tb + (size_t)c * 8) = v;
        }
#pragma unroll
        for (int i = 0; i < 4; ++i) {
            int c = i * 256 + tid;
            int fl = c & 31, hi = (c >> 5) & 1, frag = c >> 6;
            int ft = frag >> 1, ks = frag & 1;
            int f = ft * 32 + fl, k0 = ks * 16 + hi * 8;
            h8v v;
#pragma unroll
            for (int j = 0; j < 8; ++j) v[j] = (_Float16)Y[k0 + j][f];
            *(h8v*)(yB + tb + (size_t)c * 8) = v;
        }
    }
}

// ---------------------------------------------------------------------------
// flash9: R7's flash5 verbatim (proven 57.6us). grid 256 (qb,b,z)
// XCD-grouped; 512 thr = 8 waves x 32 q; gll dbuf 64-key supers; P via
// per-wave Pls; __expf softmax; defer-max thr=8.
__global__ __launch_bounds__(512) void flash9(
    const _Float16* __restrict__ q16, const _Float16* __restrict__ yA,
    const _Float16* __restrict__ yB, _Float16* __restrict__ part,
    float* __restrict__ ml)
{
    __shared__ _Float16 Asb[2][2][8192];   // 64KB
    __shared__ _Float16 Bsb[2][2][8192];   // 64KB
    __shared__ _Float16 Pls[8][1024];      // 16KB

    const int tid = threadIdx.x;
    const int w = tid >> 6, lane = tid & 63;
    const int q32 = lane & 31, hi = lane >> 5;

    int id = blockIdx.x;
    int xcd = id & 7, slot = id >> 3;
    int grp = xcd + 8 * (slot >> 2);
    int qb = slot & 3;
    int b = grp >> 2, z = grp & 3;
    const int qw = qb * 256 + w * 32;

    h8v qf[16];
    {
        const _Float16* qp = q16 + ((size_t)b * LQ + qw + q32) * 256 + hi * 8;
#pragma unroll
        for (int s = 0; s < 16; ++s) qf[s] = *(const h8v*)(qp + s * 16);
    }
    f16f ctx[8];
#pragma unroll
    for (int i = 0; i < 8; ++i) ctx[i] = (f16f){};
    float mrun = -3.0e38f, lrun = 0.f;

    const size_t tbe = (size_t)(b * 64 + z * 16) * 8192;

    auto STAGE = [&](int sup, int buf) {
#pragma unroll
        for (int j = 0; j < 2; ++j) {
            const _Float16* ga = yA + tbe + (size_t)(sup * 2 + j) * 8192 + tid * 8;
            const _Float16* gb = yB + tbe + (size_t)(sup * 2 + j) * 8192 + tid * 8;
            gll16(ga,        &Asb[buf][j][tid * 8]);
            gll16(ga + 4096, &Asb[buf][j][tid * 8 + 4096]);
            gll16(gb,        &Bsb[buf][j][tid * 8]);
            gll16(gb + 4096, &Bsb[buf][j][tid * 8 + 4096]);
        }
    };

    STAGE(0, 0);
    __syncthreads();

    int buf = 0;
    for (int s = 0; s < 8; ++s) {
        if (s < 7) STAGE(s + 1, buf ^ 1);
#pragma unroll
        for (int j = 0; j < 2; ++j) {
            const _Float16* Ap = &Asb[buf][j][0];
            const _Float16* Bp = &Bsb[buf][j][0];
            // ---- scores: S^T[32k][32q], A = y frags (LDS), B = qf (regs)
            f16f S = (f16f){};
#pragma unroll
            for (int fs = 0; fs < 16; ++fs) {
                h8v a = *(const h8v*)(Ap + fs * 512 + lane * 8);
                S = MF32(a, qf[fs], S);
            }
            // ---- softmax (per-lane col q = q32), defer-max thr=8
            float mt = S[0];
#pragma unroll
            for (int r = 1; r < 16; ++r) mt = fmaxf(mt, S[r]);
            mt = fmaxf(mt, __shfl_xor(mt, 32));
            if (!__all(mt <= mrun + 8.f)) {
                float mnew = fmaxf(mrun, mt);
                float alpha = __expf(mrun - mnew);
                lrun *= alpha;
#pragma unroll
                for (int r = 0; r < 16; ++r) {
                    int qr = (r & 3) + 8 * (r >> 2) + 4 * hi;
                    float ar = __shfl(alpha, qr);
#pragma unroll
                    for (int ft = 0; ft < 8; ++ft) ctx[ft][r] *= ar;
                }
                mrun = mnew;
            }
            float p[16], ps = 0.f;
#pragma unroll
            for (int r = 0; r < 16; ++r) { p[r] = __expf(S[r] - mrun); ps += p[r]; }
            ps += __shfl_xor(ps, 32);
            lrun += ps;
            // ---- P -> per-wave LDS (PV A-frag layout)
            {
                _Float16* pw = &Pls[w][0];
#pragma unroll
                for (int r2 = 0; r2 < 4; ++r2) {
                    h4v pk = (h4v){(_Float16)p[4 * r2], (_Float16)p[4 * r2 + 1],
                                   (_Float16)p[4 * r2 + 2], (_Float16)p[4 * r2 + 3]};
                    *(h4v*)(pw + (r2 >> 1) * 512 + (r2 & 1) * 256 + q32 * 8 + hi * 4) = pk;
                }
            }
            // ---- PV: ctx += P[32q][32k] y[32k][32f]
#pragma unroll
            for (int ks = 0; ks < 2; ++ks) {
                h8v pa = *(const h8v*)(&Pls[w][ks * 512] + lane * 8);
#pragma unroll
                for (int ft = 0; ft < 8; ++ft) {
                    h8v bf = *(const h8v*)(Bp + (ft * 2 + ks) * 512 + lane * 8);
                    ctx[ft] = MF32(pa, bf, ctx[ft]);
                }
            }
        }
        __syncthreads();
        buf ^= 1;
    }

    // ---- epilogue: normalized partials + (m, l)
    float linv = 1.f / lrun;
    _Float16* pp = part + ((size_t)z * (BB * LQ) + (size_t)b * LQ + qw) * 256;
#pragma unroll
    for (int r = 0; r < 16; ++r) {
        int qr = (r & 3) + 8 * (r >> 2) + 4 * hi;
        float ir = __shfl(linv, qr);
#pragma unroll
        for (int ft = 0; ft < 8; ++ft)
            pp[(size_t)qr * 256 + ft * 32 + q32] = (_Float16)(ctx[ft][r] * ir);
    }
    if (hi == 0) {
        size_t mi = (size_t)z * (BB * LQ) + (size_t)b * LQ + qw + q32;
        ml[2 * mi + 0] = mrun;
        ml[2 * mi + 1] = lrun;
    }
}

// ---------------------------------------------------------------------------
// gemm2c2: out[i][e] = sum_f combine(part)[i][f] Nt[e][f] + cvec[e].
// 32-row x full-512-col blocks, grid 512 = 2 blocks/CU; part read once.
__global__ __launch_bounds__(256) void gemm2c2(
    const _Float16* __restrict__ part, const float* __restrict__ ml,
    const u16* __restrict__ Ntb, const float* __restrict__ cvec,
    float* __restrict__ out)
{
    __shared__ _Float16 Asb[32][40];
    __shared__ float scl[32][4];
    const int tid = threadIdx.x;
    const int w = tid >> 6, lane = tid & 63;
    const int g = lane >> 4, qn = lane & 15;
    const int m0 = blockIdx.x * 32;
    constexpr size_t PL = (size_t)BB * LQ * F;
    constexpr size_t PR = (size_t)BB * LQ;

    if (tid < 32) {
        size_t i = m0 + tid;
        float m0v = ml[2 * i], l0v = ml[2 * i + 1];
        float m1v = ml[2 * (PR + i)], l1v = ml[2 * (PR + i) + 1];
        float m2v = ml[2 * (2 * PR + i)], l2v = ml[2 * (2 * PR + i) + 1];
        float m3v = ml[2 * (3 * PR + i)], l3v = ml[2 * (3 * PR + i) + 1];
        float M = fmaxf(fmaxf(m0v, m1v), fmaxf(m2v, m3v));
        float e0v = __expf(m0v - M), e1v = __expf(m1v - M);
        float e2v = __expf(m2v - M), e3v = __expf(m3v - M);
        float inv = 1.f / (l0v * e0v + l1v * e1v + l2v * e2v + l3v * e3v);
        scl[tid][0] = l0v * e0v * inv;
        scl[tid][1] = l1v * e1v * inv;
        scl[tid][2] = l2v * e2v * inv;
        scl[tid][3] = l3v * e3v * inv;
    }

    f4v acc[2][8];
#pragma unroll
    for (int i = 0; i < 2; ++i)
#pragma unroll
        for (int j = 0; j < 8; ++j) acc[i][j] = (f4v){0.f, 0.f, 0.f, 0.f};

    for (int k0 = 0; k0 < F; k0 += 32) {
        __syncthreads();
        {
            int r = tid >> 3, cc = (tid & 7) * 4;
            size_t base = (size_t)(m0 + r) * F + k0 + cc;
            h4v p0 = *(const h4v*)(part + base);
            h4v p1 = *(const h4v*)(part + PL + base);
            h4v p2 = *(const h4v*)(part + 2 * PL + base);
            h4v p3 = *(const h4v*)(part + 3 * PL + base);
            float s0 = scl[r][0], s1 = scl[r][1], s2 = scl[r][2], s3 = scl[r][3];
#pragma unroll
            for (int i = 0; i < 4; ++i) {
                float v = (float)p0[i] * s0 + (float)p1[i] * s1 +
                          (float)p2[i] * s2 + (float)p3[i] * s3;
                Asb[r][cc + i] = (_Float16)v;
            }
        }
        __syncthreads();

        h8v ah[2];
#pragma unroll
        for (int mt = 0; mt < 2; ++mt)
            ah[mt] = *(const h8v*)&Asb[mt * 16 + qn][g * 8];
#pragma unroll
        for (int nt = 0; nt < 8; ++nt) {
            h8v bh = *(const h8v*)((const _Float16*)Ntb +
                     (size_t)((k0 >> 5) * 32 + w * 8 + nt) * 512 + lane * 8);
            acc[0][nt] = MF16(ah[0], bh, acc[0][nt]);
            acc[1][nt] = MF16(ah[1], bh, acc[1][nt]);
        }
    }

#pragma unroll
    for (int mt = 0; mt < 2; ++mt)
#pragma unroll
        for (int nt = 0; nt < 8; ++nt)
#pragma unroll
            for (int r = 0; r < 4; ++r) {
                int gm = m0 + mt * 16 + 4 * g + r;
                int gn = w * 128 + nt * 16 + qn;
                out[(size_t)gm * E + gn] = acc[mt][nt][r] + cvec[gn];
            }
}

// ---------------------------------------------------------------------------
extern "C" void kernel_launch(void* const* d_in, const int* in_sizes, int n_in,
                              void* d_out, int out_size, void* d_ws, size_t ws_size,
                              hipStream_t stream)
{
    const float* x  = (const float*)d_in[0];   // [B,LQ,E]
    const float* y  = (const float*)d_in[1];   // [B,LK,F]
    const float* Wq = (const float*)d_in[2];
    const float* bq = (const float*)d_in[3];
    const float* Wk = (const float*)d_in[4];
    // d_in[5] = bk: per-row constant in scores -> softmax-invariant, unused.
    const float* Wv = (const float*)d_in[6];
    const float* bv = (const float*)d_in[7];
    const float* Wo = (const float*)d_in[8];
    const float* bo = (const float*)d_in[9];
    float* out = (float*)d_out;

    char* ws = (char*)d_ws;
    size_t off = 0;
    auto alloc = [&](size_t bytes) -> char* {
        char* p = ws + off;
        off = (off + bytes + 255) & ~(size_t)255;
        return p;
    };
    u16* Mhb  = (u16*)alloc(sizeof(u16) * F * E);
    float* wvec = (float*)alloc(sizeof(float) * F);
    float* cvec = (float*)alloc(sizeof(float) * E);
    u16* Ntb  = (u16*)alloc(sizeof(u16) * E * F);
    _Float16* q16 = (_Float16*)alloc(sizeof(u16) * (size_t)BB * LQ * F);
    _Float16* yA  = (_Float16*)alloc(sizeof(u16) * (size_t)BB * LK * F);
    _Float16* yB  = (_Float16*)alloc(sizeof(u16) * (size_t)BB * LK * F);
    _Float16* part = (_Float16*)alloc(sizeof(u16) * 4 * (size_t)BB * LQ * F);
    float* ml = (float*)alloc(sizeof(float) * 2 * 4 * (size_t)BB * LQ);
    (void)ws_size; (void)in_sizes; (void)n_in; (void)out_size;

    wgemm<<<dim3(67), dim3(256), 0, stream>>>(
        Wq, bq, Wk, Wv, bv, Wo, bo, Mhb, Ntb, wvec, cvec);
    prepq<<<dim3(1536), dim3(256), 0, stream>>>(
        y, yA, yB, x, Mhb, wvec, q16);
    flash9<<<dim3(256), dim3(512), 0, stream>>>(q16, yA, yB, part, ml);
    gemm2c2<<<dim3(BB * LQ / 32), dim3(256), 0, stream>>>(
        part, ml, Ntb, cvec, out);
}

// Round 13
// 132.319 us; speedup vs baseline: 1.3201x; 1.0155x over previous
//
#include <hip/hip_runtime.h>

// CrossAttentionModel on MI355X (gfx950) — round 13.
//
// Math (softmax row-constant invariance + sum(w)=1):
//   Mt[f][e] = sum_a Wk[f][a] Wq[e][a]   (split-bf16 3-pass, stored fp16)
//   wvec[f]  = Wk bq ; cvec[e] = bv Wo + bo
//   q'[i][f] = sum_e x[i][e] Mt[f][e] + wvec[f]   (fp16)
//   scores   = q' y^T  (32x32x16 fp16 MFMA)
//   out      = (softmax(scores) y) (Wv Wo) + cvec
//
// R13: launch split reverted to R11's empirically better prew(wgemm||yprep)
// -> qprime6 -> flash -> gemm2c2. flash9s = proven flash9 + T5 s_setprio
// around both MFMA clusters (guide m191: +4-7% on multi-wave attn) — the
// last isolated flash lever; everything else unchanged (clean A/B).

#define DEV static __device__ __forceinline__

typedef __attribute__((ext_vector_type(8))) short s8v;        // 8 bf16
typedef __attribute__((ext_vector_type(8))) _Float16 h8v;     // 8 fp16
typedef __attribute__((ext_vector_type(4))) _Float16 h4v;
typedef __attribute__((ext_vector_type(4))) float f4v;
typedef __attribute__((ext_vector_type(16))) float f16f;
typedef __attribute__((ext_vector_type(4))) float float4v;
typedef unsigned short u16;
typedef unsigned int u32;

constexpr int BB = 16;
constexpr int LQ = 1024;
constexpr int LK = 2048;
constexpr int E = 512;
constexpr int F = 256;

DEV u16 f2bf(float x) {
    u32 u = __builtin_bit_cast(u32, x);
    u += 0x7fff + ((u >> 16) & 1);
    return (u16)(u >> 16);
}
DEV float bf2f(u16 h) { return __builtin_bit_cast(float, (u32)h << 16); }

DEV f4v MF(s8v a, s8v b, f4v c) {
    return __builtin_amdgcn_mfma_f32_16x16x32_bf16(a, b, c, 0, 0, 0);
}
DEV f4v MF16(h8v a, h8v b, f4v c) {
    return __builtin_amdgcn_mfma_f32_16x16x32_f16(a, b, c, 0, 0, 0);
}
DEV f16f MF32(h8v a, h8v b, f16f c) {
    return __builtin_amdgcn_mfma_f32_32x32x16_f16(a, b, c, 0, 0, 0);
}

// global -> LDS async copy, 16 bytes per lane.
DEV void gll16(const _Float16* g, _Float16* l) {
    __builtin_amdgcn_global_load_lds(
        (const __attribute__((address_space(1))) u32*)g,
        (__attribute__((address_space(3))) u32*)l, 16, 0, 0);
}

// ---------------------------------------------------------------------------
// prew: fused weight preprocessing (bi>=1024) + y fragment prep (bi<1024).
// Weight GEMM blocks hide under the memory-bound y-prep population.
__global__ __launch_bounds__(256) void prew(
    const float* __restrict__ y, _Float16* __restrict__ yA,
    _Float16* __restrict__ yB,
    const float* __restrict__ Wq, const float* __restrict__ bq,
    const float* __restrict__ Wk, const float* __restrict__ Wv,
    const float* __restrict__ bv, const float* __restrict__ Wo,
    const float* __restrict__ bo,
    u16* __restrict__ Mhb, u16* __restrict__ Ntb,
    float* __restrict__ wvec, float* __restrict__ cvec)
{
    __shared__ __align__(16) char smem[33536];
    const int tid = threadIdx.x;
    const int bi = blockIdx.x;

    if (bi < 1024) {
        float (*Y)[260] = (float(*)[260])smem;
        const int b = bi >> 6, t = bi & 63;
        const float* src = y + ((size_t)b * LK + t * 32) * F;
#pragma unroll
        for (int i = 0; i < 8; ++i) {
            int base = i * 1024 + tid * 4;
            int k = base >> 8, f = base & 255;
            *(float4v*)&Y[k][f] = *(const float4v*)(src + base);
        }
        __syncthreads();
        size_t tb = (size_t)(b * 64 + t) * 8192;
#pragma unroll
        for (int i = 0; i < 4; ++i) {
            int c = i * 256 + tid;
            int k = c & 31, hi = (c >> 5) & 1, fs = c >> 6;
            int f0 = fs * 16 + hi * 8;
            float4v v0 = *(const float4v*)&Y[k][f0];
            float4v v1 = *(const float4v*)&Y[k][f0 + 4];
            h8v v;
#pragma unroll
            for (int j = 0; j < 4; ++j) { v[j] = (_Float16)v0[j]; v[4 + j] = (_Float16)v1[j]; }
            *(h8v*)(yA + tb + (size_t)c * 8) = v;
        }
#pragma unroll
        for (int i = 0; i < 4; ++i) {
            int c = i * 256 + tid;
            int fl = c & 31, hi = (c >> 5) & 1, frag = c >> 6;
            int ft = frag >> 1, ks = frag & 1;
            int f = ft * 32 + fl, k0 = ks * 16 + hi * 8;
            h8v v;
#pragma unroll
            for (int j = 0; j < 8; ++j) v[j] = (_Float16)Y[k0 + j][f];
            *(h8v*)(yB + tb + (size_t)c * 8) = v;
        }
        return;
    }

    const int wb = bi - 1024;
    if (wb >= 64) {
        if (wb == 64) {
            const float* r = Wk + (size_t)tid * 512;
            float s = 0.f;
#pragma unroll 4
            for (int a = 0; a < 512; a += 4) {
                float4v v = *(const float4v*)(r + a);
                float4v bb = *(const float4v*)(bq + a);
                s += v[0] * bb[0] + v[1] * bb[1] + v[2] * bb[2] + v[3] * bb[3];
            }
            wvec[tid] = s;
        } else {
            int e = (wb - 65) * 256 + tid;
            float s = bo[e];
#pragma unroll 4
            for (int a = 0; a < 512; ++a) s += bv[a] * Wo[(size_t)a * 512 + e];
            cvec[e] = s;
        }
        return;
    }

    const bool ntm = wb >= 32;
    const int bj = ntm ? wb - 32 : wb;
    const int m0 = ntm ? (bj >> 2) * 64 : (bj >> 3) * 64;
    const int n0 = ntm ? (bj & 3) * 64 : (bj & 7) * 64;
    const float* Ag = ntm ? Wo : Wk;
    const float* Bg = ntm ? Wv : Wq;

    u16 (*Ash)[40] = (u16(*)[40])(smem);
    u16 (*Asl)[40] = (u16(*)[40])(smem + 5120);
    u16 (*Bsh)[40] = (u16(*)[40])(smem + 10240);
    u16 (*Bsl)[40] = (u16(*)[40])(smem + 15360);

    const int w = tid >> 6, lane = tid & 63;
    const int g = lane >> 4, qn = lane & 15;
    const int wr = w & 1, wc = w >> 1;

    f4v acc[2][2];
#pragma unroll
    for (int i = 0; i < 2; ++i)
#pragma unroll
        for (int j = 0; j < 2; ++j) acc[i][j] = (f4v){0.f, 0.f, 0.f, 0.f};

    for (int k0 = 0; k0 < 512; k0 += 32) {
        __syncthreads();
        if (!ntm) {
            int r = tid & 63, c = (tid >> 6) * 8;
            const float* s = Ag + (size_t)(m0 + r) * 512 + k0 + c;
            float4v v0 = *(const float4v*)s, v1 = *(const float4v*)(s + 4);
            short hh[8], ll[8];
#pragma unroll
            for (int i = 0; i < 8; ++i) {
                float x = (i < 4) ? v0[i] : v1[i - 4];
                u16 h = f2bf(x);
                hh[i] = (short)h;
                ll[i] = (short)f2bf(x - bf2f(h));
            }
            *(s8v*)&Ash[r][c] = (s8v){hh[0],hh[1],hh[2],hh[3],hh[4],hh[5],hh[6],hh[7]};
            *(s8v*)&Asl[r][c] = (s8v){ll[0],ll[1],ll[2],ll[3],ll[4],ll[5],ll[6],ll[7]};
        } else {
            int k = tid >> 3, mc = (tid & 7) * 8;
            const float* s = Ag + (size_t)(k0 + k) * 512 + m0 + mc;
            float4v v0 = *(const float4v*)s, v1 = *(const float4v*)(s + 4);
#pragma unroll
            for (int i = 0; i < 8; ++i) {
                float x = (i < 4) ? v0[i] : v1[i - 4];
                u16 h = f2bf(x);
                Ash[mc + i][k] = h;
                Asl[mc + i][k] = f2bf(x - bf2f(h));
            }
        }
        {
            int r = tid & 63, c = (tid >> 6) * 8;
            const float* s = Bg + (size_t)(n0 + r) * 512 + k0 + c;
            float4v v0 = *(const float4v*)s, v1 = *(const float4v*)(s + 4);
            short hh[8], ll[8];
#pragma unroll
            for (int i = 0; i < 8; ++i) {
                float x = (i < 4) ? v0[i] : v1[i - 4];
                u16 h = f2bf(x);
                hh[i] = (short)h;
                ll[i] = (short)f2bf(x - bf2f(h));
            }
            *(s8v*)&Bsh[r][c] = (s8v){hh[0],hh[1],hh[2],hh[3],hh[4],hh[5],hh[6],hh[7]};
            *(s8v*)&Bsl[r][c] = (s8v){ll[0],ll[1],ll[2],ll[3],ll[4],ll[5],ll[6],ll[7]};
        }
        __syncthreads();

        s8v ah[2], al[2], bh[2], bl[2];
#pragma unroll
        for (int mt = 0; mt < 2; ++mt) {
            ah[mt] = *(const s8v*)&Ash[wr * 32 + mt * 16 + qn][g * 8];
            al[mt] = *(const s8v*)&Asl[wr * 32 + mt * 16 + qn][g * 8];
        }
#pragma unroll
        for (int nt = 0; nt < 2; ++nt) {
            bh[nt] = *(const s8v*)&Bsh[wc * 32 + nt * 16 + qn][g * 8];
            bl[nt] = *(const s8v*)&Bsl[wc * 32 + nt * 16 + qn][g * 8];
        }
#pragma unroll
        for (int mt = 0; mt < 2; ++mt)
#pragma unroll
            for (int nt = 0; nt < 2; ++nt) {
                acc[mt][nt] = MF(ah[mt], bh[nt], acc[mt][nt]);
                acc[mt][nt] = MF(ah[mt], bl[nt], acc[mt][nt]);
                acc[mt][nt] = MF(al[mt], bh[nt], acc[mt][nt]);
            }
    }

#pragma unroll
    for (int mt = 0; mt < 2; ++mt)
#pragma unroll
        for (int nt = 0; nt < 2; ++nt)
#pragma unroll
            for (int r = 0; r < 4; ++r) {
                int gm = m0 + wr * 32 + mt * 16 + 4 * g + r;
                int gn = n0 + wc * 32 + nt * 16 + qn;
                float v = acc[mt][nt][r];
                if (!ntm) {
                    size_t off = (size_t)((gn >> 5) * 16 + (gm >> 4)) * 512 +
                                 (gm & 15) * 8 + ((gn >> 3) & 3) * 128 + (gn & 7);
                    Mhb[off] = __builtin_bit_cast(u16, (_Float16)v);
                } else {
                    size_t off = (size_t)((gn >> 5) * 32 + (gm >> 4)) * 512 +
                                 (gm & 15) * 8 + ((gn >> 3) & 3) * 128 + (gn & 7);
                    Ntb[off] = __builtin_bit_cast(u16, (_Float16)v);
                }
            }
}

// ---------------------------------------------------------------------------
// qprime6: q' = x @ Mt + wvec -> fp16. 64-row tiles, grid (256, 2).
// B-frag register double-buffer.
__global__ __launch_bounds__(256) void qprime6(
    const float* __restrict__ x, const u16* __restrict__ Mhb,
    const float* __restrict__ wv, _Float16* __restrict__ q16)
{
    __shared__ _Float16 Xs[2][64][40];
    const int tid = threadIdx.x, w = tid >> 6, lane = tid & 63;
    const int g = lane >> 4, qn = lane & 15;
    const int m0 = blockIdx.x * 64;
    const int nh = blockIdx.y * 8;
    const int srow = tid >> 2, scol = (tid & 3) * 8;
    const _Float16* Mh = (const _Float16*)Mhb;

    f4v acc[8];
#pragma unroll
    for (int n = 0; n < 8; ++n) acc[n] = (f4v){0.f, 0.f, 0.f, 0.f};

    float4v a0, a1;
    auto LDA = [&](int k0) {
        const float* s = x + (size_t)(m0 + srow) * 512 + k0 + scol;
        a0 = *(const float4v*)s;
        a1 = *(const float4v*)(s + 4);
    };
    auto STA = [&](int buf) {
        h8v v;
#pragma unroll
        for (int j = 0; j < 4; ++j) { v[j] = (_Float16)a0[j]; v[4 + j] = (_Float16)a1[j]; }
        *(h8v*)&Xs[buf][srow][scol] = v;
    };
    h8v b0[8], b1[8];
    auto LDB0 = [&](int t) {
        const int fb = t * 16 + nh;
#pragma unroll
        for (int nt = 0; nt < 8; ++nt)
            b0[nt] = *(const h8v*)(Mh + (size_t)(fb + nt) * 512 + lane * 8);
    };
    auto LDB1 = [&](int t) {
        const int fb = t * 16 + nh;
#pragma unroll
        for (int nt = 0; nt < 8; ++nt)
            b1[nt] = *(const h8v*)(Mh + (size_t)(fb + nt) * 512 + lane * 8);
    };

    LDA(0); STA(0); LDA(32); LDB0(0);
    __syncthreads();

#pragma unroll
    for (int t = 0; t < 16; ++t) {
        const int cur = t & 1;
        if (t < 15) { if (cur == 0) LDB1(t + 1); else LDB0(t + 1); }
        h8v af = *(const h8v*)&Xs[cur][w * 16 + qn][g * 8];
        if (cur == 0) {
#pragma unroll
            for (int nt = 0; nt < 8; ++nt) acc[nt] = MF16(af, b0[nt], acc[nt]);
        } else {
#pragma unroll
            for (int nt = 0; nt < 8; ++nt) acc[nt] = MF16(af, b1[nt], acc[nt]);
        }
        if (t < 15) {
            STA(cur ^ 1);
            if (t < 14) LDA((t + 2) * 32);
            __syncthreads();
        }
    }

#pragma unroll
    for (int nt = 0; nt < 8; ++nt) {
        int col = (nh + nt) * 16 + qn;
        float wvc = wv[col];
#pragma unroll
        for (int r = 0; r < 4; ++r) {
            int row = m0 + w * 16 + 4 * g + r;
            q16[(size_t)row * 256 + col] = (_Float16)(acc[nt][r] + wvc);
        }
    }
}

// ---------------------------------------------------------------------------
// flash9s: R7/R12's proven flash (57.6us) + T5 s_setprio around both MFMA
// clusters (only change). grid 256 (qb,b,z) XCD-grouped; 512 thr = 8 waves
// x 32 q; gll dbuf 64-key supers; __expf; defer-max thr=8.
__global__ __launch_bounds__(512) void flash9s(
    const _Float16* __restrict__ q16, const _Float16* __restrict__ yA,
    const _Float16* __restrict__ yB, _Float16* __restrict__ part,
    float* __restrict__ ml)
{
    __shared__ _Float16 Asb[2][2][8192];   // 64KB
    __shared__ _Float16 Bsb[2][2][8192];   // 64KB
    __shared__ _Float16 Pls[8][1024];      // 16KB

    const int tid = threadIdx.x;
    const int w = tid >> 6, lane = tid & 63;
    const int q32 = lane & 31, hi = lane >> 5;

    int id = blockIdx.x;
    int xcd = id & 7, slot = id >> 3;
    int grp = xcd + 8 * (slot >> 2);
    int qb = slot & 3;
    int b = grp >> 2, z = grp & 3;
    const int qw = qb * 256 + w * 32;

    h8v qf[16];
    {
        const _Float16* qp = q16 + ((size_t)b * LQ + qw + q32) * 256 + hi * 8;
#pragma unroll
        for (int s = 0; s < 16; ++s) qf[s] = *(const h8v*)(qp + s * 16);
    }
    f16f ctx[8];
#pragma unroll
    for (int i = 0; i < 8; ++i) ctx[i] = (f16f){};
    float mrun = -3.0e38f, lrun = 0.f;

    const size_t tbe = (size_t)(b * 64 + z * 16) * 8192;

    auto STAGE = [&](int sup, int buf) {
#pragma unroll
        for (int j = 0; j < 2; ++j) {
            const _Float16* ga = yA + tbe + (size_t)(sup * 2 + j) * 8192 + tid * 8;
            const _Float16* gb = yB + tbe + (size_t)(sup * 2 + j) * 8192 + tid * 8;
            gll16(ga,        &Asb[buf][j][tid * 8]);
            gll16(ga + 4096, &Asb[buf][j][tid * 8 + 4096]);
            gll16(gb,        &Bsb[buf][j][tid * 8]);
            gll16(gb + 4096, &Bsb[buf][j][tid * 8 + 4096]);
        }
    };

    STAGE(0, 0);
    __syncthreads();

    int buf = 0;
    for (int s = 0; s < 8; ++s) {
        if (s < 7) STAGE(s + 1, buf ^ 1);
#pragma unroll
        for (int j = 0; j < 2; ++j) {
            const _Float16* Ap = &Asb[buf][j][0];
            const _Float16* Bp = &Bsb[buf][j][0];
            // ---- scores: S^T[32k][32q], A = y frags (LDS), B = qf (regs)
            f16f S = (f16f){};
            __builtin_amdgcn_s_setprio(1);
#pragma unroll
            for (int fs = 0; fs < 16; ++fs) {
                h8v a = *(const h8v*)(Ap + fs * 512 + lane * 8);
                S = MF32(a, qf[fs], S);
            }
            __builtin_amdgcn_s_setprio(0);
            // ---- softmax (per-lane col q = q32), defer-max thr=8
            float mt = S[0];
#pragma unroll
            for (int r = 1; r < 16; ++r) mt = fmaxf(mt, S[r]);
            mt = fmaxf(mt, __shfl_xor(mt, 32));
            if (!__all(mt <= mrun + 8.f)) {
                float mnew = fmaxf(mrun, mt);
                float alpha = __expf(mrun - mnew);
                lrun *= alpha;
#pragma unroll
                for (int r = 0; r < 16; ++r) {
                    int qr = (r & 3) + 8 * (r >> 2) + 4 * hi;
                    float ar = __shfl(alpha, qr);
#pragma unroll
                    for (int ft = 0; ft < 8; ++ft) ctx[ft][r] *= ar;
                }
                mrun = mnew;
            }
            float p[16], ps = 0.f;
#pragma unroll
            for (int r = 0; r < 16; ++r) { p[r] = __expf(S[r] - mrun); ps += p[r]; }
            ps += __shfl_xor(ps, 32);
            lrun += ps;
            // ---- P -> per-wave LDS (PV A-frag layout)
            {
                _Float16* pw = &Pls[w][0];
#pragma unroll
                for (int r2 = 0; r2 < 4; ++r2) {
                    h4v pk = (h4v){(_Float16)p[4 * r2], (_Float16)p[4 * r2 + 1],
                                   (_Float16)p[4 * r2 + 2], (_Float16)p[4 * r2 + 3]};
                    *(h4v*)(pw + (r2 >> 1) * 512 + (r2 & 1) * 256 + q32 * 8 + hi * 4) = pk;
                }
            }
            // ---- PV: ctx += P[32q][32k] y[32k][32f]
            __builtin_amdgcn_s_setprio(1);
#pragma unroll
            for (int ks = 0; ks < 2; ++ks) {
                h8v pa = *(const h8v*)(&Pls[w][ks * 512] + lane * 8);
#pragma unroll
                for (int ft = 0; ft < 8; ++ft) {
                    h8v bf = *(const h8v*)(Bp + (ft * 2 + ks) * 512 + lane * 8);
                    ctx[ft] = MF32(pa, bf, ctx[ft]);
                }
            }
            __builtin_amdgcn_s_setprio(0);
        }
        __syncthreads();
        buf ^= 1;
    }

    // ---- epilogue: normalized partials + (m, l)
    float linv = 1.f / lrun;
    _Float16* pp = part + ((size_t)z * (BB * LQ) + (size_t)b * LQ + qw) * 256;
#pragma unroll
    for (int r = 0; r < 16; ++r) {
        int qr = (r & 3) + 8 * (r >> 2) + 4 * hi;
        float ir = __shfl(linv, qr);
#pragma unroll
        for (int ft = 0; ft < 8; ++ft)
            pp[(size_t)qr * 256 + ft * 32 + q32] = (_Float16)(ctx[ft][r] * ir);
    }
    if (hi == 0) {
        size_t mi = (size_t)z * (BB * LQ) + (size_t)b * LQ + qw + q32;
        ml[2 * mi + 0] = mrun;
        ml[2 * mi + 1] = lrun;
    }
}

// ---------------------------------------------------------------------------
// gemm2c2: out[i][e] = sum_f combine(part)[i][f] Nt[e][f] + cvec[e].
// 32-row x full-512-col blocks, grid 512; part read once.
__global__ __launch_bounds__(256) void gemm2c2(
    const _Float16* __restrict__ part, const float* __restrict__ ml,
    const u16* __restrict__ Ntb, const float* __restrict__ cvec,
    float* __restrict__ out)
{
    __shared__ _Float16 Asb[32][40];
    __shared__ float scl[32][4];
    const int tid = threadIdx.x;
    const int w = tid >> 6, lane = tid & 63;
    const int g = lane >> 4, qn = lane & 15;
    const int m0 = blockIdx.x * 32;
    constexpr size_t PL = (size_t)BB * LQ * F;
    constexpr size_t PR = (size_t)BB * LQ;

    if (tid < 32) {
        size_t i = m0 + tid;
        float m0v = ml[2 * i], l0v = ml[2 * i + 1];
        float m1v = ml[2 * (PR + i)], l1v = ml[2 * (PR + i) + 1];
        float m2v = ml[2 * (2 * PR + i)], l2v = ml[2 * (2 * PR + i) + 1];
        float m3v = ml[2 * (3 * PR + i)], l3v = ml[2 * (3 * PR + i) + 1];
        float M = fmaxf(fmaxf(m0v, m1v), fmaxf(m2v, m3v));
        float e0v = __expf(m0v - M), e1v = __expf(m1v - M);
        float e2v = __expf(m2v - M), e3v = __expf(m3v - M);
        float inv = 1.f / (l0v * e0v + l1v * e1v + l2v * e2v + l3v * e3v);
        scl[tid][0] = l0v * e0v * inv;
        scl[tid][1] = l1v * e1v * inv;
        scl[tid][2] = l2v * e2v * inv;
        scl[tid][3] = l3v * e3v * inv;
    }

    f4v acc[2][8];
#pragma unroll
    for (int i = 0; i < 2; ++i)
#pragma unroll
        for (int j = 0; j < 8; ++j) acc[i][j] = (f4v){0.f, 0.f, 0.f, 0.f};

    for (int k0 = 0; k0 < F; k0 += 32) {
        __syncthreads();
        {
            int r = tid >> 3, cc = (tid & 7) * 4;
            size_t base = (size_t)(m0 + r) * F + k0 + cc;
            h4v p0 = *(const h4v*)(part + base);
            h4v p1 = *(const h4v*)(part + PL + base);
            h4v p2 = *(const h4v*)(part + 2 * PL + base);
            h4v p3 = *(const h4v*)(part + 3 * PL + base);
            float s0 = scl[r][0], s1 = scl[r][1], s2 = scl[r][2], s3 = scl[r][3];
#pragma unroll
            for (int i = 0; i < 4; ++i) {
                float v = (float)p0[i] * s0 + (float)p1[i] * s1 +
                          (float)p2[i] * s2 + (float)p3[i] * s3;
                Asb[r][cc + i] = (_Float16)v;
            }
        }
        __syncthreads();

        h8v ah[2];
#pragma unroll
        for (int mt = 0; mt < 2; ++mt)
            ah[mt] = *(const h8v*)&Asb[mt * 16 + qn][g * 8];
#pragma unroll
        for (int nt = 0; nt < 8; ++nt) {
            h8v bh = *(const h8v*)((const _Float16*)Ntb +
                     (size_t)((k0 >> 5) * 32 + w * 8 + nt) * 512 + lane * 8);
            acc[0][nt] = MF16(ah[0], bh, acc[0][nt]);
            acc[1][nt] = MF16(ah[1], bh, acc[1][nt]);
        }
    }

#pragma unroll
    for (int mt = 0; mt < 2; ++mt)
#pragma unroll
        for (int nt = 0; nt < 8; ++nt)
#pragma unroll
            for (int r = 0; r < 4; ++r) {
                int gm = m0 + mt * 16 + 4 * g + r;
                int gn = w * 128 + nt * 16 + qn;
                out[(size_t)gm * E + gn] = acc[mt][nt][r] + cvec[gn];
            }
}

// ---------------------------------------------------------------------------
extern "C" void kernel_launch(void* const* d_in, const int* in_sizes, int n_in,
                              void* d_out, int out_size, void* d_ws, size_t ws_size,
                              hipStream_t stream)
{
    const float* x  = (const float*)d_in[0];   // [B,LQ,E]
    const float* y  = (const float*)d_in[1];   // [B,LK,F]
    const float* Wq = (const float*)d_in[2];
    const float* bq = (const float*)d_in[3];
    const float* Wk = (const float*)d_in[4];
    // d_in[5] = bk: per-row constant in scores -> softmax-invariant, unused.
    const float* Wv = (const float*)d_in[6];
    const float* bv = (const float*)d_in[7];
    const float* Wo = (const float*)d_in[8];
    const float* bo = (const float*)d_in[9];
    float* out = (float*)d_out;

    char* ws = (char*)d_ws;
    size_t off = 0;
    auto alloc = [&](size_t bytes) -> char* {
        char* p = ws + off;
        off = (off + bytes + 255) & ~(size_t)255;
        return p;
    };
    u16* Mhb  = (u16*)alloc(sizeof(u16) * F * E);
    float* wvec = (float*)alloc(sizeof(float) * F);
    float* cvec = (float*)alloc(sizeof(float) * E);
    u16* Ntb  = (u16*)alloc(sizeof(u16) * E * F);
    _Float16* q16 = (_Float16*)alloc(sizeof(u16) * (size_t)BB * LQ * F);
    _Float16* yA  = (_Float16*)alloc(sizeof(u16) * (size_t)BB * LK * F);
    _Float16* yB  = (_Float16*)alloc(sizeof(u16) * (size_t)BB * LK * F);
    _Float16* part = (_Float16*)alloc(sizeof(u16) * 4 * (size_t)BB * LQ * F);
    float* ml = (float*)alloc(sizeof(float) * 2 * 4 * (size_t)BB * LQ);
    (void)ws_size; (void)in_sizes; (void)n_in; (void)out_size;

    prew<<<dim3(1091), dim3(256), 0, stream>>>(
        y, yA, yB, Wq, bq, Wk, Wv, bv, Wo, bo, Mhb, Ntb, wvec, cvec);
    qprime6<<<dim3(BB * LQ / 64, 2), dim3(256), 0, stream>>>(x, Mhb, wvec, q16);
    flash9s<<<dim3(256), dim3(512), 0, stream>>>(q16, yA, yB, part, ml);
    gemm2c2<<<dim3(BB * LQ / 32), dim3(256), 0, stream>>>(
        part, ml, Ntb, cvec, out);
}

// Round 14
// 130.885 us; speedup vs baseline: 1.3345x; 1.0110x over previous
//
#include <hip/hip_runtime.h>

// CrossAttentionModel on MI355X (gfx950) — round 14.
//
// Math (softmax row-constant invariance + sum(w)=1):
//   Mt[f][e] = sum_a Wk[f][a] Wq[e][a]   (split-bf16 3-pass, stored fp16)
//   wvec[f]  = Wk bq ; cvec[e] = bv Wo + bo
//   q'[i][f] = sum_e x[i][e] Mt[f][e] + wvec[f]   (fp16)
//   scores   = q' y^T  (32x32x16 fp16 MFMA)
//   out      = (softmax(scores) y) (Wv Wo) + cvec
//
// R14 vs R13 (flash plateau confirmed — 7 variants at 57.5±0.3):
//  1. prew2: wgemm blocks moved to bi<67 (FRONT of grid) so their ~6us runs
//     concurrently with the 1024 memory-bound y-prep blocks, not as a
//     64-CU serial tail.
//  2. qprime7: 1D grid with XCD-aware swizzle pairing the two nh-halves of
//     each row-block on the SAME XCD -> second read of x hits that XCD's L2
//     (x HBM traffic 67 -> ~34MB).
//  flash9s / gemm2c2 unchanged.

#define DEV static __device__ __forceinline__

typedef __attribute__((ext_vector_type(8))) short s8v;        // 8 bf16
typedef __attribute__((ext_vector_type(8))) _Float16 h8v;     // 8 fp16
typedef __attribute__((ext_vector_type(4))) _Float16 h4v;
typedef __attribute__((ext_vector_type(4))) float f4v;
typedef __attribute__((ext_vector_type(16))) float f16f;
typedef __attribute__((ext_vector_type(4))) float float4v;
typedef unsigned short u16;
typedef unsigned int u32;

constexpr int BB = 16;
constexpr int LQ = 1024;
constexpr int LK = 2048;
constexpr int E = 512;
constexpr int F = 256;

DEV u16 f2bf(float x) {
    u32 u = __builtin_bit_cast(u32, x);
    u += 0x7fff + ((u >> 16) & 1);
    return (u16)(u >> 16);
}
DEV float bf2f(u16 h) { return __builtin_bit_cast(float, (u32)h << 16); }

DEV f4v MF(s8v a, s8v b, f4v c) {
    return __builtin_amdgcn_mfma_f32_16x16x32_bf16(a, b, c, 0, 0, 0);
}
DEV f4v MF16(h8v a, h8v b, f4v c) {
    return __builtin_amdgcn_mfma_f32_16x16x32_f16(a, b, c, 0, 0, 0);
}
DEV f16f MF32(h8v a, h8v b, f16f c) {
    return __builtin_amdgcn_mfma_f32_32x32x16_f16(a, b, c, 0, 0, 0);
}

// global -> LDS async copy, 16 bytes per lane.
DEV void gll16(const _Float16* g, _Float16* l) {
    __builtin_amdgcn_global_load_lds(
        (const __attribute__((address_space(1))) u32*)g,
        (__attribute__((address_space(3))) u32*)l, 16, 0, 0);
}

// ---------------------------------------------------------------------------
// prew2: weight preprocessing FIRST (bi<67: co-schedules with y-prep from
// t=0), y fragment prep bi 67..1090.
__global__ __launch_bounds__(256) void prew2(
    const float* __restrict__ y, _Float16* __restrict__ yA,
    _Float16* __restrict__ yB,
    const float* __restrict__ Wq, const float* __restrict__ bq,
    const float* __restrict__ Wk, const float* __restrict__ Wv,
    const float* __restrict__ bv, const float* __restrict__ Wo,
    const float* __restrict__ bo,
    u16* __restrict__ Mhb, u16* __restrict__ Ntb,
    float* __restrict__ wvec, float* __restrict__ cvec)
{
    __shared__ __align__(16) char smem[33536];
    const int tid = threadIdx.x;
    const int bi = blockIdx.x;

    if (bi >= 67) {
        // ---------------- y-prep ----------------
        const int pb = bi - 67;
        float (*Y)[260] = (float(*)[260])smem;
        const int b = pb >> 6, t = pb & 63;
        const float* src = y + ((size_t)b * LK + t * 32) * F;
#pragma unroll
        for (int i = 0; i < 8; ++i) {
            int base = i * 1024 + tid * 4;
            int k = base >> 8, f = base & 255;
            *(float4v*)&Y[k][f] = *(const float4v*)(src + base);
        }
        __syncthreads();
        size_t tb = (size_t)(b * 64 + t) * 8192;
#pragma unroll
        for (int i = 0; i < 4; ++i) {
            int c = i * 256 + tid;
            int k = c & 31, hi = (c >> 5) & 1, fs = c >> 6;
            int f0 = fs * 16 + hi * 8;
            float4v v0 = *(const float4v*)&Y[k][f0];
            float4v v1 = *(const float4v*)&Y[k][f0 + 4];
            h8v v;
#pragma unroll
            for (int j = 0; j < 4; ++j) { v[j] = (_Float16)v0[j]; v[4 + j] = (_Float16)v1[j]; }
            *(h8v*)(yA + tb + (size_t)c * 8) = v;
        }
#pragma unroll
        for (int i = 0; i < 4; ++i) {
            int c = i * 256 + tid;
            int fl = c & 31, hi = (c >> 5) & 1, frag = c >> 6;
            int ft = frag >> 1, ks = frag & 1;
            int f = ft * 32 + fl, k0 = ks * 16 + hi * 8;
            h8v v;
#pragma unroll
            for (int j = 0; j < 8; ++j) v[j] = (_Float16)Y[k0 + j][f];
            *(h8v*)(yB + tb + (size_t)c * 8) = v;
        }
        return;
    }

    if (bi >= 64) {
        if (bi == 64) {
            const float* r = Wk + (size_t)tid * 512;
            float s = 0.f;
#pragma unroll 4
            for (int a = 0; a < 512; a += 4) {
                float4v v = *(const float4v*)(r + a);
                float4v bb = *(const float4v*)(bq + a);
                s += v[0] * bb[0] + v[1] * bb[1] + v[2] * bb[2] + v[3] * bb[3];
            }
            wvec[tid] = s;
        } else {
            int e = (bi - 65) * 256 + tid;
            float s = bo[e];
#pragma unroll 4
            for (int a = 0; a < 512; ++a) s += bv[a] * Wo[(size_t)a * 512 + e];
            cvec[e] = s;
        }
        return;
    }

    // ---------------- wgemm 64x64 tile (bi 0..63) ----------------
    const bool ntm = bi >= 32;
    const int bj = ntm ? bi - 32 : bi;
    const int m0 = ntm ? (bj >> 2) * 64 : (bj >> 3) * 64;
    const int n0 = ntm ? (bj & 3) * 64 : (bj & 7) * 64;
    const float* Ag = ntm ? Wo : Wk;
    const float* Bg = ntm ? Wv : Wq;

    u16 (*Ash)[40] = (u16(*)[40])(smem);
    u16 (*Asl)[40] = (u16(*)[40])(smem + 5120);
    u16 (*Bsh)[40] = (u16(*)[40])(smem + 10240);
    u16 (*Bsl)[40] = (u16(*)[40])(smem + 15360);

    const int w = tid >> 6, lane = tid & 63;
    const int g = lane >> 4, qn = lane & 15;
    const int wr = w & 1, wc = w >> 1;

    f4v acc[2][2];
#pragma unroll
    for (int i = 0; i < 2; ++i)
#pragma unroll
        for (int j = 0; j < 2; ++j) acc[i][j] = (f4v){0.f, 0.f, 0.f, 0.f};

    for (int k0 = 0; k0 < 512; k0 += 32) {
        __syncthreads();
        if (!ntm) {
            int r = tid & 63, c = (tid >> 6) * 8;
            const float* s = Ag + (size_t)(m0 + r) * 512 + k0 + c;
            float4v v0 = *(const float4v*)s, v1 = *(const float4v*)(s + 4);
            short hh[8], ll[8];
#pragma unroll
            for (int i = 0; i < 8; ++i) {
                float x = (i < 4) ? v0[i] : v1[i - 4];
                u16 h = f2bf(x);
                hh[i] = (short)h;
                ll[i] = (short)f2bf(x - bf2f(h));
            }
            *(s8v*)&Ash[r][c] = (s8v){hh[0],hh[1],hh[2],hh[3],hh[4],hh[5],hh[6],hh[7]};
            *(s8v*)&Asl[r][c] = (s8v){ll[0],ll[1],ll[2],ll[3],ll[4],ll[5],ll[6],ll[7]};
        } else {
            int k = tid >> 3, mc = (tid & 7) * 8;
            const float* s = Ag + (size_t)(k0 + k) * 512 + m0 + mc;
            float4v v0 = *(const float4v*)s, v1 = *(const float4v*)(s + 4);
#pragma unroll
            for (int i = 0; i < 8; ++i) {
                float x = (i < 4) ? v0[i] : v1[i - 4];
                u16 h = f2bf(x);
                Ash[mc + i][k] = h;
                Asl[mc + i][k] = f2bf(x - bf2f(h));
            }
        }
        {
            int r = tid & 63, c = (tid >> 6) * 8;
            const float* s = Bg + (size_t)(n0 + r) * 512 + k0 + c;
            float4v v0 = *(const float4v*)s, v1 = *(const float4v*)(s + 4);
            short hh[8], ll[8];
#pragma unroll
            for (int i = 0; i < 8; ++i) {
                float x = (i < 4) ? v0[i] : v1[i - 4];
                u16 h = f2bf(x);
                hh[i] = (short)h;
                ll[i] = (short)f2bf(x - bf2f(h));
            }
            *(s8v*)&Bsh[r][c] = (s8v){hh[0],hh[1],hh[2],hh[3],hh[4],hh[5],hh[6],hh[7]};
            *(s8v*)&Bsl[r][c] = (s8v){ll[0],ll[1],ll[2],ll[3],ll[4],ll[5],ll[6],ll[7]};
        }
        __syncthreads();

        s8v ah[2], al[2], bh[2], bl[2];
#pragma unroll
        for (int mt = 0; mt < 2; ++mt) {
            ah[mt] = *(const s8v*)&Ash[wr * 32 + mt * 16 + qn][g * 8];
            al[mt] = *(const s8v*)&Asl[wr * 32 + mt * 16 + qn][g * 8];
        }
#pragma unroll
        for (int nt = 0; nt < 2; ++nt) {
            bh[nt] = *(const s8v*)&Bsh[wc * 32 + nt * 16 + qn][g * 8];
            bl[nt] = *(const s8v*)&Bsl[wc * 32 + nt * 16 + qn][g * 8];
        }
#pragma unroll
        for (int mt = 0; mt < 2; ++mt)
#pragma unroll
            for (int nt = 0; nt < 2; ++nt) {
                acc[mt][nt] = MF(ah[mt], bh[nt], acc[mt][nt]);
                acc[mt][nt] = MF(ah[mt], bl[nt], acc[mt][nt]);
                acc[mt][nt] = MF(al[mt], bh[nt], acc[mt][nt]);
            }
    }

#pragma unroll
    for (int mt = 0; mt < 2; ++mt)
#pragma unroll
        for (int nt = 0; nt < 2; ++nt)
#pragma unroll
            for (int r = 0; r < 4; ++r) {
                int gm = m0 + wr * 32 + mt * 16 + 4 * g + r;
                int gn = n0 + wc * 32 + nt * 16 + qn;
                float v = acc[mt][nt][r];
                if (!ntm) {
                    size_t off = (size_t)((gn >> 5) * 16 + (gm >> 4)) * 512 +
                                 (gm & 15) * 8 + ((gn >> 3) & 3) * 128 + (gn & 7);
                    Mhb[off] = __builtin_bit_cast(u16, (_Float16)v);
                } else {
                    size_t off = (size_t)((gn >> 5) * 32 + (gm >> 4)) * 512 +
                                 (gm & 15) * 8 + ((gn >> 3) & 3) * 128 + (gn & 7);
                    Ntb[off] = __builtin_bit_cast(u16, (_Float16)v);
                }
            }
}

// ---------------------------------------------------------------------------
// qprime7: q' = x @ Mt + wvec -> fp16. 64-row tiles. 1D grid 512, XCD-aware
// swizzle: logical = (id&7)*64 + (id>>3), so the two nh-halves of each
// row-block (logical 2k, 2k+1) run on the SAME XCD -> x read #2 is L2-hot.
// B-frag register double-buffer (unchanged body).
__global__ __launch_bounds__(256) void qprime7(
    const float* __restrict__ x, const u16* __restrict__ Mhb,
    const float* __restrict__ wv, _Float16* __restrict__ q16)
{
    __shared__ _Float16 Xs[2][64][40];
    const int tid = threadIdx.x, w = tid >> 6, lane = tid & 63;
    const int g = lane >> 4, qn = lane & 15;
    const int id = blockIdx.x;
    const int logical = (id & 7) * 64 + (id >> 3);   // 512 blocks, 64 per XCD
    const int m0 = (logical >> 1) * 64;
    const int nh = (logical & 1) * 8;
    const int srow = tid >> 2, scol = (tid & 3) * 8;
    const _Float16* Mh = (const _Float16*)Mhb;

    f4v acc[8];
#pragma unroll
    for (int n = 0; n < 8; ++n) acc[n] = (f4v){0.f, 0.f, 0.f, 0.f};

    float4v a0, a1;
    auto LDA = [&](int k0) {
        const float* s = x + (size_t)(m0 + srow) * 512 + k0 + scol;
        a0 = *(const float4v*)s;
        a1 = *(const float4v*)(s + 4);
    };
    auto STA = [&](int buf) {
        h8v v;
#pragma unroll
        for (int j = 0; j < 4; ++j) { v[j] = (_Float16)a0[j]; v[4 + j] = (_Float16)a1[j]; }
        *(h8v*)&Xs[buf][srow][scol] = v;
    };
    h8v b0[8], b1[8];
    auto LDB0 = [&](int t) {
        const int fb = t * 16 + nh;
#pragma unroll
        for (int nt = 0; nt < 8; ++nt)
            b0[nt] = *(const h8v*)(Mh + (size_t)(fb + nt) * 512 + lane * 8);
    };
    auto LDB1 = [&](int t) {
        const int fb = t * 16 + nh;
#pragma unroll
        for (int nt = 0; nt < 8; ++nt)
            b1[nt] = *(const h8v*)(Mh + (size_t)(fb + nt) * 512 + lane * 8);
    };

    LDA(0); STA(0); LDA(32); LDB0(0);
    __syncthreads();

#pragma unroll
    for (int t = 0; t < 16; ++t) {
        const int cur = t & 1;
        if (t < 15) { if (cur == 0) LDB1(t + 1); else LDB0(t + 1); }
        h8v af = *(const h8v*)&Xs[cur][w * 16 + qn][g * 8];
        if (cur == 0) {
#pragma unroll
            for (int nt = 0; nt < 8; ++nt) acc[nt] = MF16(af, b0[nt], acc[nt]);
        } else {
#pragma unroll
            for (int nt = 0; nt < 8; ++nt) acc[nt] = MF16(af, b1[nt], acc[nt]);
        }
        if (t < 15) {
            STA(cur ^ 1);
            if (t < 14) LDA((t + 2) * 32);
            __syncthreads();
        }
    }

#pragma unroll
    for (int nt = 0; nt < 8; ++nt) {
        int col = (nh + nt) * 16 + qn;
        float wvc = wv[col];
#pragma unroll
        for (int r = 0; r < 4; ++r) {
            int row = m0 + w * 16 + 4 * g + r;
            q16[(size_t)row * 256 + col] = (_Float16)(acc[nt][r] + wvc);
        }
    }
}

// ---------------------------------------------------------------------------
// flash9s (unchanged, proven 57.5us): grid 256 (qb,b,z) XCD-grouped; 512 thr
// = 8 waves x 32 q; gll dbuf 64-key supers; __expf; defer-max thr=8.
__global__ __launch_bounds__(512) void flash9s(
    const _Float16* __restrict__ q16, const _Float16* __restrict__ yA,
    const _Float16* __restrict__ yB, _Float16* __restrict__ part,
    float* __restrict__ ml)
{
    __shared__ _Float16 Asb[2][2][8192];   // 64KB
    __shared__ _Float16 Bsb[2][2][8192];   // 64KB
    __shared__ _Float16 Pls[8][1024];      // 16KB

    const int tid = threadIdx.x;
    const int w = tid >> 6, lane = tid & 63;
    const int q32 = lane & 31, hi = lane >> 5;

    int id = blockIdx.x;
    int xcd = id & 7, slot = id >> 3;
    int grp = xcd + 8 * (slot >> 2);
    int qb = slot & 3;
    int b = grp >> 2, z = grp & 3;
    const int qw = qb * 256 + w * 32;

    h8v qf[16];
    {
        const _Float16* qp = q16 + ((size_t)b * LQ + qw + q32) * 256 + hi * 8;
#pragma unroll
        for (int s = 0; s < 16; ++s) qf[s] = *(const h8v*)(qp + s * 16);
    }
    f16f ctx[8];
#pragma unroll
    for (int i = 0; i < 8; ++i) ctx[i] = (f16f){};
    float mrun = -3.0e38f, lrun = 0.f;

    const size_t tbe = (size_t)(b * 64 + z * 16) * 8192;

    auto STAGE = [&](int sup, int buf) {
#pragma unroll
        for (int j = 0; j < 2; ++j) {
            const _Float16* ga = yA + tbe + (size_t)(sup * 2 + j) * 8192 + tid * 8;
            const _Float16* gb = yB + tbe + (size_t)(sup * 2 + j) * 8192 + tid * 8;
            gll16(ga,        &Asb[buf][j][tid * 8]);
            gll16(ga + 4096, &Asb[buf][j][tid * 8 + 4096]);
            gll16(gb,        &Bsb[buf][j][tid * 8]);
            gll16(gb + 4096, &Bsb[buf][j][tid * 8 + 4096]);
        }
    };

    STAGE(0, 0);
    __syncthreads();

    int buf = 0;
    for (int s = 0; s < 8; ++s) {
        if (s < 7) STAGE(s + 1, buf ^ 1);
#pragma unroll
        for (int j = 0; j < 2; ++j) {
            const _Float16* Ap = &Asb[buf][j][0];
            const _Float16* Bp = &Bsb[buf][j][0];
            // ---- scores: S^T[32k][32q], A = y frags (LDS), B = qf (regs)
            f16f S = (f16f){};
            __builtin_amdgcn_s_setprio(1);
#pragma unroll
            for (int fs = 0; fs < 16; ++fs) {
                h8v a = *(const h8v*)(Ap + fs * 512 + lane * 8);
                S = MF32(a, qf[fs], S);
            }
            __builtin_amdgcn_s_setprio(0);
            // ---- softmax (per-lane col q = q32), defer-max thr=8
            float mt = S[0];
#pragma unroll
            for (int r = 1; r < 16; ++r) mt = fmaxf(mt, S[r]);
            mt = fmaxf(mt, __shfl_xor(mt, 32));
            if (!__all(mt <= mrun + 8.f)) {
                float mnew = fmaxf(mrun, mt);
                float alpha = __expf(mrun - mnew);
                lrun *= alpha;
#pragma unroll
                for (int r = 0; r < 16; ++r) {
                    int qr = (r & 3) + 8 * (r >> 2) + 4 * hi;
                    float ar = __shfl(alpha, qr);
#pragma unroll
                    for (int ft = 0; ft < 8; ++ft) ctx[ft][r] *= ar;
                }
                mrun = mnew;
            }
            float p[16], ps = 0.f;
#pragma unroll
            for (int r = 0; r < 16; ++r) { p[r] = __expf(S[r] - mrun); ps += p[r]; }
            ps += __shfl_xor(ps, 32);
            lrun += ps;
            // ---- P -> per-wave LDS (PV A-frag layout)
            {
                _Float16* pw = &Pls[w][0];
#pragma unroll
                for (int r2 = 0; r2 < 4; ++r2) {
                    h4v pk = (h4v){(_Float16)p[4 * r2], (_Float16)p[4 * r2 + 1],
                                   (_Float16)p[4 * r2 + 2], (_Float16)p[4 * r2 + 3]};
                    *(h4v*)(pw + (r2 >> 1) * 512 + (r2 & 1) * 256 + q32 * 8 + hi * 4) = pk;
                }
            }
            // ---- PV: ctx += P[32q][32k] y[32k][32f]
            __builtin_amdgcn_s_setprio(1);
#pragma unroll
            for (int ks = 0; ks < 2; ++ks) {
                h8v pa = *(const h8v*)(&Pls[w][ks * 512] + lane * 8);
#pragma unroll
                for (int ft = 0; ft < 8; ++ft) {
                    h8v bf = *(const h8v*)(Bp + (ft * 2 + ks) * 512 + lane * 8);
                    ctx[ft] = MF32(pa, bf, ctx[ft]);
                }
            }
            __builtin_amdgcn_s_setprio(0);
        }
        __syncthreads();
        buf ^= 1;
    }

    // ---- epilogue: normalized partials + (m, l)
    float linv = 1.f / lrun;
    _Float16* pp = part + ((size_t)z * (BB * LQ) + (size_t)b * LQ + qw) * 256;
#pragma unroll
    for (int r = 0; r < 16; ++r) {
        int qr = (r & 3) + 8 * (r >> 2) + 4 * hi;
        float ir = __shfl(linv, qr);
#pragma unroll
        for (int ft = 0; ft < 8; ++ft)
            pp[(size_t)qr * 256 + ft * 32 + q32] = (_Float16)(ctx[ft][r] * ir);
    }
    if (hi == 0) {
        size_t mi = (size_t)z * (BB * LQ) + (size_t)b * LQ + qw + q32;
        ml[2 * mi + 0] = mrun;
        ml[2 * mi + 1] = lrun;
    }
}

// ---------------------------------------------------------------------------
// gemm2c2 (unchanged): out[i][e] = sum_f combine(part)[i][f] Nt[e][f] +
// cvec[e]. 32-row x full-512-col blocks, grid 512; part read once.
__global__ __launch_bounds__(256) void gemm2c2(
    const _Float16* __restrict__ part, const float* __restrict__ ml,
    const u16* __restrict__ Ntb, const float* __restrict__ cvec,
    float* __restrict__ out)
{
    __shared__ _Float16 Asb[32][40];
    __shared__ float scl[32][4];
    const int tid = threadIdx.x;
    const int w = tid >> 6, lane = tid & 63;
    const int g = lane >> 4, qn = lane & 15;
    const int m0 = blockIdx.x * 32;
    constexpr size_t PL = (size_t)BB * LQ * F;
    constexpr size_t PR = (size_t)BB * LQ;

    if (tid < 32) {
        size_t i = m0 + tid;
        float m0v = ml[2 * i], l0v = ml[2 * i + 1];
        float m1v = ml[2 * (PR + i)], l1v = ml[2 * (PR + i) + 1];
        float m2v = ml[2 * (2 * PR + i)], l2v = ml[2 * (2 * PR + i) + 1];
        float m3v = ml[2 * (3 * PR + i)], l3v = ml[2 * (3 * PR + i) + 1];
        float M = fmaxf(fmaxf(m0v, m1v), fmaxf(m2v, m3v));
        float e0v = __expf(m0v - M), e1v = __expf(m1v - M);
        float e2v = __expf(m2v - M), e3v = __expf(m3v - M);
        float inv = 1.f / (l0v * e0v + l1v * e1v + l2v * e2v + l3v * e3v);
        scl[tid][0] = l0v * e0v * inv;
        scl[tid][1] = l1v * e1v * inv;
        scl[tid][2] = l2v * e2v * inv;
        scl[tid][3] = l3v * e3v * inv;
    }

    f4v acc[2][8];
#pragma unroll
    for (int i = 0; i < 2; ++i)
#pragma unroll
        for (int j = 0; j < 8; ++j) acc[i][j] = (f4v){0.f, 0.f, 0.f, 0.f};

    for (int k0 = 0; k0 < F; k0 += 32) {
        __syncthreads();
        {
            int r = tid >> 3, cc = (tid & 7) * 4;
            size_t base = (size_t)(m0 + r) * F + k0 + cc;
            h4v p0 = *(const h4v*)(part + base);
            h4v p1 = *(const h4v*)(part + PL + base);
            h4v p2 = *(const h4v*)(part + 2 * PL + base);
            h4v p3 = *(const h4v*)(part + 3 * PL + base);
            float s0 = scl[r][0], s1 = scl[r][1], s2 = scl[r][2], s3 = scl[r][3];
#pragma unroll
            for (int i = 0; i < 4; ++i) {
                float v = (float)p0[i] * s0 + (float)p1[i] * s1 +
                          (float)p2[i] * s2 + (float)p3[i] * s3;
                Asb[r][cc + i] = (_Float16)v;
            }
        }
        __syncthreads();

        h8v ah[2];
#pragma unroll
        for (int mt = 0; mt < 2; ++mt)
            ah[mt] = *(const h8v*)&Asb[mt * 16 + qn][g * 8];
#pragma unroll
        for (int nt = 0; nt < 8; ++nt) {
            h8v bh = *(const h8v*)((const _Float16*)Ntb +
                     (size_t)((k0 >> 5) * 32 + w * 8 + nt) * 512 + lane * 8);
            acc[0][nt] = MF16(ah[0], bh, acc[0][nt]);
            acc[1][nt] = MF16(ah[1], bh, acc[1][nt]);
        }
    }

#pragma unroll
    for (int mt = 0; mt < 2; ++mt)
#pragma unroll
        for (int nt = 0; nt < 8; ++nt)
#pragma unroll
            for (int r = 0; r < 4; ++r) {
                int gm = m0 + mt * 16 + 4 * g + r;
                int gn = w * 128 + nt * 16 + qn;
                out[(size_t)gm * E + gn] = acc[mt][nt][r] + cvec[gn];
            }
}

// ---------------------------------------------------------------------------
extern "C" void kernel_launch(void* const* d_in, const int* in_sizes, int n_in,
                              void* d_out, int out_size, void* d_ws, size_t ws_size,
                              hipStream_t stream)
{
    const float* x  = (const float*)d_in[0];   // [B,LQ,E]
    const float* y  = (const float*)d_in[1];   // [B,LK,F]
    const float* Wq = (const float*)d_in[2];
    const float* bq = (const float*)d_in[3];
    const float* Wk = (const float*)d_in[4];
    // d_in[5] = bk: per-row constant in scores -> softmax-invariant, unused.
    const float* Wv = (const float*)d_in[6];
    const float* bv = (const float*)d_in[7];
    const float* Wo = (const float*)d_in[8];
    const float* bo = (const float*)d_in[9];
    float* out = (float*)d_out;

    char* ws = (char*)d_ws;
    size_t off = 0;
    auto alloc = [&](size_t bytes) -> char* {
        char* p = ws + off;
        off = (off + bytes + 255) & ~(size_t)255;
        return p;
    };
    u16* Mhb  = (u16*)alloc(sizeof(u16) * F * E);
    float* wvec = (float*)alloc(sizeof(float) * F);
    float* cvec = (float*)alloc(sizeof(float) * E);
    u16* Ntb  = (u16*)alloc(sizeof(u16) * E * F);
    _Float16* q16 = (_Float16*)alloc(sizeof(u16) * (size_t)BB * LQ * F);
    _Float16* yA  = (_Float16*)alloc(sizeof(u16) * (size_t)BB * LK * F);
    _Float16* yB  = (_Float16*)alloc(sizeof(u16) * (size_t)BB * LK * F);
    _Float16* part = (_Float16*)alloc(sizeof(u16) * 4 * (size_t)BB * LQ * F);
    float* ml = (float*)alloc(sizeof(float) * 2 * 4 * (size_t)BB * LQ);
    (void)ws_size; (void)in_sizes; (void)n_in; (void)out_size;

    prew2<<<dim3(1091), dim3(256), 0, stream>>>(
        y, yA, yB, Wq, bq, Wk, Wv, bv, Wo, bo, Mhb, Ntb, wvec, cvec);
    qprime7<<<dim3(512), dim3(256), 0, stream>>>(x, Mhb, wvec, q16);
    flash9s<<<dim3(256), dim3(512), 0, stream>>>(q16, yA, yB, part, ml);
    gemm2c2<<<dim3(BB * LQ / 32), dim3(256), 0, stream>>>(
        part, ml, Ntb, cvec, out);
}